// Round 10
// baseline (555.567 us; speedup 1.0000x reference)
//
#include <hip/hip_runtime.h>
#include <math.h>

#define NT 4096      // B*T
#define DD 1024      // D == DM
#define NH 16
#define HSZ 64
#define GN_EPS 1e-5f
#define DECAY_C -0.606531f

typedef __attribute__((ext_vector_type(8))) short short8;
typedef __attribute__((ext_vector_type(4))) float float4v;

#define GLB(p) ((const __attribute__((address_space(1))) void*)(p))
#define LDS(p) ((__attribute__((address_space(3))) void*)(p))

#define MEMFENCE asm volatile("" ::: "memory")

__device__ __forceinline__ float sigm(float x) { return 1.f / (1.f + __expf(-x)); }

__device__ __forceinline__ unsigned short f2bf(float f) {
    unsigned int u = __float_as_uint(f);
    u = (u + 0x7fffu + ((u >> 16) & 1u)) >> 16;
    return (unsigned short)u;
}
__device__ __forceinline__ float bf2f(unsigned short h) {
    return __uint_as_float(((unsigned int)h) << 16);
}

// Full sum across each 16-lane row via DPP row_ror rotate-adds (VALU pipe only)
__device__ __forceinline__ float row_sum16(float x) {
    int t;
    t = __builtin_amdgcn_update_dpp(0, __float_as_int(x), 0x128, 0xF, 0xF, true); // ror 8
    x += __int_as_float(t);
    t = __builtin_amdgcn_update_dpp(0, __float_as_int(x), 0x124, 0xF, 0xF, true); // ror 4
    x += __int_as_float(t);
    t = __builtin_amdgcn_update_dpp(0, __float_as_int(x), 0x122, 0xF, 0xF, true); // ror 2
    x += __int_as_float(t);
    t = __builtin_amdgcn_update_dpp(0, __float_as_int(x), 0x121, 0xF, 0xF, true); // ror 1
    x += __int_as_float(t);
    return x;
}

// ---------------- fused 6-branch mix + hi/lo split-cast
__global__ __launch_bounds__(256)
void mix6(const float* __restrict__ cur, const float* __restrict__ prev,
          const float* __restrict__ lam,
          ushort* __restrict__ xrh, ushort* __restrict__ xrl,
          ushort* __restrict__ xwh, ushort* __restrict__ xwl,
          ushort* __restrict__ xkh, ushort* __restrict__ xkl,
          ushort* __restrict__ xvh, ushort* __restrict__ xvl,
          ushort* __restrict__ xah, ushort* __restrict__ xal,
          ushort* __restrict__ xgh, ushort* __restrict__ xgl)
{
    const int tok = blockIdx.x;
    const int d0 = threadIdx.x * 4;
    const size_t base = (size_t)tok * DD + d0;
    float4 c = *(const float4*)(cur + base);
    float4 p = *(const float4*)(prev + base);
    float dx = p.x - c.x, dy = p.y - c.y, dz = p.z - c.z, dw = p.w - c.w;
    ushort* hs[6] = {xrh, xwh, xkh, xvh, xah, xgh};
    ushort* ls[6] = {xrl, xwl, xkl, xvl, xal, xgl};
#pragma unroll
    for (int j = 0; j < 6; j++) {
        float4 l = *(const float4*)(lam + j * DD + d0);
        float m0 = c.x + l.x * dx;
        float m1 = c.y + l.y * dy;
        float m2 = c.z + l.z * dz;
        float m3 = c.w + l.w * dw;
        ushort4 h;
        h.x = f2bf(m0); h.y = f2bf(m1); h.z = f2bf(m2); h.w = f2bf(m3);
        *(ushort4*)(hs[j] + base) = h;
        ushort4 lo;
        lo.x = f2bf(m0 - bf2f(h.x));
        lo.y = f2bf(m1 - bf2f(h.y));
        lo.z = f2bf(m2 - bf2f(h.z));
        lo.w = f2bf(m3 - bf2f(h.w));
        *(ushort4*)(ls[j] + base) = lo;
    }
}

// ---------------- transpose + split-cast with zero-padding:
// W[K][N] fp32 -> Wt[Npad][K] hi/lo bf16. grid.x covers Npad/32; cols >= N -> 0.
__global__ __launch_bounds__(256)
void transpose_pad(const float* __restrict__ W, ushort* __restrict__ Wh,
                   ushort* __restrict__ Wl, int K, int N)
{
    __shared__ float tile[32][33];
    const int bx = blockIdx.x * 32;  // N (padded)
    const int by = blockIdx.y * 32;  // K
    const int tx = threadIdx.x, ty = threadIdx.y;  // 32 x 8
#pragma unroll
    for (int i = 0; i < 32; i += 8) {
        float v = 0.f;
        if (bx + tx < N) v = W[(size_t)(by + ty + i) * N + bx + tx];
        tile[ty + i][tx] = v;
    }
    __syncthreads();
#pragma unroll
    for (int i = 0; i < 32; i += 8) {
        float v = tile[tx][ty + i];
        ushort h = f2bf(v);
        size_t o = (size_t)(bx + ty + i) * K + by + tx;
        Wh[o] = h;
        if (Wl) Wl[o] = f2bf(v - bf2f(h));
    }
}

// LDS chunk swizzle: row-dependent XOR on the 16B-chunk index.
// bank-group g = (row*4 + chunk) % 8; chunk = quad ^ ((row>>1)&3) spreads each
// 16-lane quarter-wave over all 8 groups (2 lanes each -> free).
#define SWZ(r) (((r) >> 1) & 3)

// ---------------- MEGA stage-1 GEMM: 128x128 tiles, double-buffered with
// COUNTED vmcnt + raw barriers (T4): no vmcnt(0) drain in the main loop.
// N = 3584 = r[0,1024) k[1024,2048) v[2048,3072) w1@3072(64) a1@3200(64)
//            v1@3328(32) g1@3456(128). K=1024, bf16x3 split, per-colblock A.
__global__ __launch_bounds__(256)
void gemm_mega1(const ushort* __restrict__ xrh, const ushort* __restrict__ xrl,
                const ushort* __restrict__ xwh, const ushort* __restrict__ xwl,
                const ushort* __restrict__ xkh, const ushort* __restrict__ xkl,
                const ushort* __restrict__ xvh, const ushort* __restrict__ xvl,
                const ushort* __restrict__ xah, const ushort* __restrict__ xal,
                const ushort* __restrict__ xgh, const ushort* __restrict__ xgl,
                const ushort* __restrict__ Bth, const ushort* __restrict__ Btl,
                float* __restrict__ r_buf, float* __restrict__ k_buf,
                float* __restrict__ v_buf,
                ushort* __restrict__ hwh, ushort* __restrict__ hwl,
                ushort* __restrict__ hah, ushort* __restrict__ hal,
                ushort* __restrict__ hvh, ushort* __restrict__ hvl,
                ushort* __restrict__ hgh, ushort* __restrict__ hgl)
{
    __shared__ ushort As[2][2][128 * 32];   // [dbuf][hi/lo]  32 KB
    __shared__ ushort Bs[2][2][128 * 32];   // 32 KB
    const int cb = blockIdx.y;
    const ushort* Ah; const ushort* Al;
    if (cb < 8)       { Ah = xrh; Al = xrl; }
    else if (cb < 16) { Ah = xkh; Al = xkl; }
    else if (cb < 24) { Ah = xvh; Al = xvl; }
    else if (cb == 24){ Ah = xwh; Al = xwl; }
    else if (cb == 25){ Ah = xah; Al = xal; }
    else if (cb == 26){ Ah = xvh; Al = xvl; }
    else              { Ah = xgh; Al = xgl; }

    const int tid = threadIdx.x;
    const int rowBase = blockIdx.x * 128;
    const int colBase = cb * 128;
    const int lane = tid & 63;
    const int wave = tid >> 6;
    const int wm = wave >> 1, wn = wave & 1;
    const int m15 = lane & 15, quad = lane >> 4;

    float4v zero4 = {0.f, 0.f, 0.f, 0.f};
    float4v acc[4][4];
#pragma unroll
    for (int i = 0; i < 4; i++)
#pragma unroll
        for (int j = 0; j < 4; j++) acc[i][j] = zero4;

#define STAGE1(kk, bb) do {                                                       \
    const int k0_ = (kk) * 32;                                                    \
    _Pragma("unroll")                                                             \
    for (int i_ = 0; i_ < 2; i_++) {                                              \
        int idx_ = i_ * 256 + tid;                                                \
        int r_ = idx_ >> 2, seg_ = idx_ & 3;                                      \
        int sg_ = seg_ ^ SWZ(r_);   /* pre-swizzled source; LDS dest linear */    \
        size_t aoff_ = (size_t)(rowBase + r_) * 1024 + k0_ + sg_ * 8;             \
        size_t boff_ = (size_t)(colBase + r_) * 1024 + k0_ + sg_ * 8;             \
        int dst_ = (i_ * 256 + (tid & ~63)) * 8;                                  \
        __builtin_amdgcn_global_load_lds(GLB(Ah + aoff_),  LDS(&As[bb][0][0] + dst_), 16, 0, 0); \
        __builtin_amdgcn_global_load_lds(GLB(Al + aoff_),  LDS(&As[bb][1][0] + dst_), 16, 0, 0); \
        __builtin_amdgcn_global_load_lds(GLB(Bth + boff_), LDS(&Bs[bb][0][0] + dst_), 16, 0, 0); \
        __builtin_amdgcn_global_load_lds(GLB(Btl + boff_), LDS(&Bs[bb][1][0] + dst_), 16, 0, 0); \
    }                                                                             \
} while (0)

    STAGE1(0, 0);                       // 8 loads -> buf0
    STAGE1(1, 1);                       // 8 loads -> buf1 (16 outstanding)
    asm volatile("s_waitcnt vmcnt(8)" ::: "memory");   // buf0 landed
    __builtin_amdgcn_s_barrier();
    MEMFENCE;

    for (int kt = 0; kt < 32; kt++) {
        const int buf = kt & 1;

        short8 ah[4], bh[4], al[4], bl[4];
#pragma unroll
        for (int mi = 0; mi < 4; mi++) {
            int ra = wm * 64 + mi * 16 + m15;
            int cs = (quad ^ SWZ(ra)) * 8;
            ah[mi] = *(const short8*)(&As[buf][0][0] + ra * 32 + cs);
            al[mi] = *(const short8*)(&As[buf][1][0] + ra * 32 + cs);
        }
#pragma unroll
        for (int ni = 0; ni < 4; ni++) {
            int rb = wn * 64 + ni * 16 + m15;
            int cs = (quad ^ SWZ(rb)) * 8;
            bh[ni] = *(const short8*)(&Bs[buf][0][0] + rb * 32 + cs);
            bl[ni] = *(const short8*)(&Bs[buf][1][0] + rb * 32 + cs);
        }
#pragma unroll
        for (int mi = 0; mi < 4; mi++)
#pragma unroll
            for (int ni = 0; ni < 4; ni++) {
                acc[mi][ni] = __builtin_amdgcn_mfma_f32_16x16x32_bf16(al[mi], bh[ni], acc[mi][ni], 0, 0, 0);
                acc[mi][ni] = __builtin_amdgcn_mfma_f32_16x16x32_bf16(ah[mi], bl[ni], acc[mi][ni], 0, 0, 0);
                acc[mi][ni] = __builtin_amdgcn_mfma_f32_16x16x32_bf16(ah[mi], bh[ni], acc[mi][ni], 0, 0, 0);
            }

        if (kt == 31) break;

        MEMFENCE;
        __builtin_amdgcn_s_barrier();   // all waves done reading buf[kt]
        MEMFENCE;
        if (kt < 30) {
            STAGE1(kt + 2, buf);        // refill the buffer just read
            asm volatile("s_waitcnt vmcnt(8)" ::: "memory");  // stage(kt+1) landed
        } else {
            asm volatile("s_waitcnt vmcnt(0)" ::: "memory");  // stage(31) landed
        }
        __builtin_amdgcn_s_barrier();   // buf[kt+1] ready for everyone
        MEMFENCE;
    }
#undef STAGE1

#pragma unroll
    for (int mi = 0; mi < 4; mi++) {
#pragma unroll
        for (int ni = 0; ni < 4; ni++) {
            int c = wn * 64 + ni * 16 + m15;   // col within 128-tile
#pragma unroll
            for (int rr = 0; rr < 4; rr++) {
                int row = rowBase + wm * 64 + mi * 16 + quad * 4 + rr;
                float v = acc[mi][ni][rr];
                if (cb < 24) {
                    float* dst = (cb < 8) ? r_buf : (cb < 16) ? k_buf : v_buf;
                    int n = (cb & 7) * 128 + c;
                    dst[(size_t)row * 1024 + n] = v;
                } else if (cb == 24) {
                    if (c < 64) {
                        float t = tanhf(v);
                        ushort h = f2bf(t);
                        hwh[(size_t)row * 64 + c] = h;
                        hwl[(size_t)row * 64 + c] = f2bf(t - bf2f(h));
                    }
                } else if (cb == 25) {
                    if (c < 64) {
                        ushort h = f2bf(v);
                        hah[(size_t)row * 64 + c] = h;
                        hal[(size_t)row * 64 + c] = f2bf(v - bf2f(h));
                    }
                } else if (cb == 26) {
                    if (c < 32) {
                        ushort h = f2bf(v);
                        hvh[(size_t)row * 32 + c] = h;
                        hvl[(size_t)row * 32 + c] = f2bf(v - bf2f(h));
                    }
                } else {
                    float t = sigm(v);
                    ushort h = f2bf(t);
                    hgh[(size_t)row * 128 + c] = h;
                    hgl[(size_t)row * 128 + c] = f2bf(t - bf2f(h));
                }
            }
        }
    }
}

// ---------------- MEGA stage-2 GEMM: 4 LoRA stage-2 products in one dispatch.
// blockIdx.y: 0-7 w2(K=64,none), 8-15 a2(K=64,sigm), 16-23 v2(K=32,sigm),
// 24-31 g2(K=128,none). All outputs fp32 [4096][1024].
__global__ __launch_bounds__(256)
void gemm_mega2(const ushort* __restrict__ hwh, const ushort* __restrict__ hwl,
                const ushort* __restrict__ hah, const ushort* __restrict__ hal,
                const ushort* __restrict__ hvh, const ushort* __restrict__ hvl,
                const ushort* __restrict__ hgh, const ushort* __restrict__ hgl,
                const ushort* __restrict__ w2Th, const ushort* __restrict__ w2Tl,
                const ushort* __restrict__ a2Th, const ushort* __restrict__ a2Tl,
                const ushort* __restrict__ v2Th, const ushort* __restrict__ v2Tl,
                const ushort* __restrict__ g2Th, const ushort* __restrict__ g2Tl,
                const float* __restrict__ w2_b, const float* __restrict__ a2_b,
                const float* __restrict__ v2_b, const float* __restrict__ g2_b,
                float* __restrict__ w_buf, float* __restrict__ a_buf,
                float* __restrict__ vg_buf, float* __restrict__ g_buf)
{
    __shared__ ushort AsH[128 * 32];
    __shared__ ushort BsH[128 * 32];
    __shared__ ushort AsL[128 * 32];
    __shared__ ushort BsL[128 * 32];
    const int cb = blockIdx.y;
    const int seg = cb >> 3;
    const int K = (seg == 2) ? 32 : (seg == 3) ? 128 : 64;
    const ushort *Ah, *Al, *Bh, *Bl;
    const float* bias;
    float* outp;
    if (seg == 0) { Ah = hwh; Al = hwl; Bh = w2Th; Bl = w2Tl; bias = w2_b; outp = w_buf; }
    else if (seg == 1) { Ah = hah; Al = hal; Bh = a2Th; Bl = a2Tl; bias = a2_b; outp = a_buf; }
    else if (seg == 2) { Ah = hvh; Al = hvl; Bh = v2Th; Bl = v2Tl; bias = v2_b; outp = vg_buf; }
    else { Ah = hgh; Al = hgl; Bh = g2Th; Bl = g2Tl; bias = g2_b; outp = g_buf; }

    const int tid = threadIdx.x;
    const int rowBase = blockIdx.x * 128;
    const int colBase = (cb & 7) * 128;
    const int lane = tid & 63;
    const int wave = tid >> 6;
    const int wm = wave >> 1, wn = wave & 1;
    const int m15 = lane & 15, quad = lane >> 4;

    float4v zero4 = {0.f, 0.f, 0.f, 0.f};
    float4v acc[4][4];
#pragma unroll
    for (int i = 0; i < 4; i++)
#pragma unroll
        for (int j = 0; j < 4; j++) acc[i][j] = zero4;

    for (int k0 = 0; k0 < K; k0 += 32) {
#pragma unroll
        for (int i = 0; i < 2; i++) {
            int idx = i * 256 + tid;
            int r = idx >> 2, s8 = idx & 3;
            int sg = s8 ^ SWZ(r);   // pre-swizzled source, linear LDS dest
            size_t aoff = (size_t)(rowBase + r) * K + k0 + sg * 8;
            size_t boff = (size_t)(colBase + r) * K + k0 + sg * 8;
            int dst = (i * 256 + (tid & ~63)) * 8;
            __builtin_amdgcn_global_load_lds(GLB(Ah + aoff), LDS(AsH + dst), 16, 0, 0);
            __builtin_amdgcn_global_load_lds(GLB(Bh + boff), LDS(BsH + dst), 16, 0, 0);
            __builtin_amdgcn_global_load_lds(GLB(Al + aoff), LDS(AsL + dst), 16, 0, 0);
            __builtin_amdgcn_global_load_lds(GLB(Bl + boff), LDS(BsL + dst), 16, 0, 0);
        }
        __syncthreads();
        short8 ah[4], bh[4], al[4], bl[4];
#pragma unroll
        for (int mi = 0; mi < 4; mi++) {
            int ra = wm * 64 + mi * 16 + m15;
            int cs = (quad ^ SWZ(ra)) * 8;
            ah[mi] = *(const short8*)(AsH + ra * 32 + cs);
            al[mi] = *(const short8*)(AsL + ra * 32 + cs);
        }
#pragma unroll
        for (int ni = 0; ni < 4; ni++) {
            int rb = wn * 64 + ni * 16 + m15;
            int cs = (quad ^ SWZ(rb)) * 8;
            bh[ni] = *(const short8*)(BsH + rb * 32 + cs);
            bl[ni] = *(const short8*)(BsL + rb * 32 + cs);
        }
#pragma unroll
        for (int mi = 0; mi < 4; mi++)
#pragma unroll
            for (int ni = 0; ni < 4; ni++) {
                acc[mi][ni] = __builtin_amdgcn_mfma_f32_16x16x32_bf16(al[mi], bh[ni], acc[mi][ni], 0, 0, 0);
                acc[mi][ni] = __builtin_amdgcn_mfma_f32_16x16x32_bf16(ah[mi], bl[ni], acc[mi][ni], 0, 0, 0);
                acc[mi][ni] = __builtin_amdgcn_mfma_f32_16x16x32_bf16(ah[mi], bh[ni], acc[mi][ni], 0, 0, 0);
            }
        __syncthreads();
    }

#pragma unroll
    for (int mi = 0; mi < 4; mi++) {
#pragma unroll
        for (int ni = 0; ni < 4; ni++) {
            int col = colBase + wn * 64 + ni * 16 + m15;
            float bv = bias[col];
#pragma unroll
            for (int rr = 0; rr < 4; rr++) {
                int row = rowBase + wm * 64 + mi * 16 + quad * 4 + rr;
                float v = acc[mi][ni][rr] + bv;
                if (seg == 1 || seg == 2) v = sigm(v);
                outp[(size_t)row * 1024 + col] = v;
            }
        }
    }
}

// ---------------- plain bf16 GEMM (final out-projection), counted-vmcnt dbuf
__global__ __launch_bounds__(256)
void gemm_bf16s(const ushort* __restrict__ Ah, const ushort* __restrict__ Bh,
                float* __restrict__ outF, int N, int K)
{
    __shared__ ushort As2[2][128 * 32];
    __shared__ ushort Bs2[2][128 * 32];
    const int tid = threadIdx.x;
    const int rowBase = blockIdx.x * 128;
    const int colBase = blockIdx.y * 128;
    const int lane = tid & 63;
    const int wave = tid >> 6;
    const int wm = wave >> 1, wn = wave & 1;
    const int m15 = lane & 15, quad = lane >> 4;

    float4v zero4 = {0.f, 0.f, 0.f, 0.f};
    float4v acc[4][4];
#pragma unroll
    for (int i = 0; i < 4; i++)
#pragma unroll
        for (int j = 0; j < 4; j++) acc[i][j] = zero4;

#define STAGE3(kk, bb) do {                                                       \
    const int k0_ = (kk) * 32;                                                    \
    _Pragma("unroll")                                                             \
    for (int i_ = 0; i_ < 2; i_++) {                                              \
        int idx_ = i_ * 256 + tid;                                                \
        int r_ = idx_ >> 2, seg_ = idx_ & 3;                                      \
        int sg_ = seg_ ^ SWZ(r_);                                                 \
        size_t aoff_ = (size_t)(rowBase + r_) * K + k0_ + sg_ * 8;                \
        size_t boff_ = (size_t)(colBase + r_) * K + k0_ + sg_ * 8;                \
        int dst_ = (i_ * 256 + (tid & ~63)) * 8;                                  \
        __builtin_amdgcn_global_load_lds(GLB(Ah + aoff_), LDS(&As2[bb][0] + dst_), 16, 0, 0); \
        __builtin_amdgcn_global_load_lds(GLB(Bh + boff_), LDS(&Bs2[bb][0] + dst_), 16, 0, 0); \
    }                                                                             \
} while (0)

    const int nk = K >> 5;          // 32 for K=1024
    STAGE3(0, 0);                   // 4 loads -> buf0
    STAGE3(1, 1);                   // 4 loads -> buf1 (8 outstanding)
    asm volatile("s_waitcnt vmcnt(4)" ::: "memory");   // buf0 landed
    __builtin_amdgcn_s_barrier();
    MEMFENCE;

    for (int kt = 0; kt < nk; kt++) {
        const int buf = kt & 1;
        short8 ah[4], bh[4];
#pragma unroll
        for (int mi = 0; mi < 4; mi++) {
            int ra = wm * 64 + mi * 16 + m15;
            ah[mi] = *(const short8*)(&As2[buf][0] + ra * 32 + (quad ^ SWZ(ra)) * 8);
        }
#pragma unroll
        for (int ni = 0; ni < 4; ni++) {
            int rb = wn * 64 + ni * 16 + m15;
            bh[ni] = *(const short8*)(&Bs2[buf][0] + rb * 32 + (quad ^ SWZ(rb)) * 8);
        }
#pragma unroll
        for (int mi = 0; mi < 4; mi++)
#pragma unroll
            for (int ni = 0; ni < 4; ni++)
                acc[mi][ni] = __builtin_amdgcn_mfma_f32_16x16x32_bf16(ah[mi], bh[ni], acc[mi][ni], 0, 0, 0);

        if (kt == nk - 1) break;

        MEMFENCE;
        __builtin_amdgcn_s_barrier();   // all waves done reading buf[kt]
        MEMFENCE;
        if (kt < nk - 2) {
            STAGE3(kt + 2, buf);        // refill just-read buffer (4 loads)
            asm volatile("s_waitcnt vmcnt(4)" ::: "memory");  // stage(kt+1) landed
        } else {
            asm volatile("s_waitcnt vmcnt(0)" ::: "memory");
        }
        __builtin_amdgcn_s_barrier();   // buf[kt+1] ready
        MEMFENCE;
    }
#undef STAGE3

#pragma unroll
    for (int mi = 0; mi < 4; mi++) {
#pragma unroll
        for (int ni = 0; ni < 4; ni++) {
            int col = colBase + wn * 64 + ni * 16 + m15;
#pragma unroll
            for (int rr = 0; rr < 4; rr++) {
                int row = rowBase + wm * 64 + mi * 16 + quad * 4 + rr;
                outF[(size_t)row * N + col] = acc[mi][ni][rr];
            }
        }
    }
}

// ---------------- elementwise stage 1 (fp32)
// NOTE: a_buf is OVERWRITTEN with nbt = kkn * a (pre-multiplied for scan).
__global__ __launch_bounds__(256)
void elemwise1(const float* __restrict__ r_buf, float* __restrict__ wl_buf,
               float* __restrict__ k_buf, float* __restrict__ v_buf,
               float* __restrict__ kkn_buf, float* __restrict__ a_buf,
               const float* __restrict__ vg_buf, const float* __restrict__ vfirst,
               const float* __restrict__ kkw, const float* __restrict__ kaw,
               const float* __restrict__ rkw, float* __restrict__ rk_sum)
{
    const int tok = blockIdx.x;
    const int tid = threadIdx.x;
    const int d0 = tid * 4;
    const size_t base = (size_t)tok * DD + d0;

    float4 k0 = *(const float4*)(k_buf + base);
    float4 a4 = *(const float4*)(a_buf + base);
    float4 wl = *(const float4*)(wl_buf + base);
    float4 v0 = *(const float4*)(v_buf + base);
    float4 vg = *(const float4*)(vg_buf + base);
    float4 vf = *(const float4*)(vfirst + base);
    float4 r4 = *(const float4*)(r_buf + base);
    float4 kkc = *(const float4*)(kkw + d0);
    float4 kac = *(const float4*)(kaw + d0);
    float4 rkc = *(const float4*)(rkw + d0);

    float kk0 = k0.x * kkc.x, kk1 = k0.y * kkc.y, kk2 = k0.z * kkc.z, kk3 = k0.w * kkc.w;
    float ss = kk0 * kk0 + kk1 * kk1 + kk2 * kk2 + kk3 * kk3;
    ss += __shfl_xor(ss, 1); ss += __shfl_xor(ss, 2);
    ss += __shfl_xor(ss, 4); ss += __shfl_xor(ss, 8);
    float rn = rsqrtf(ss);
    float4 kkn = { kk0 * rn, kk1 * rn, kk2 * rn, kk3 * rn };
    *(float4*)(kkn_buf + base) = kkn;

    // nbt = kkn * a  (scan uses s += sa * (-nbt) directly)
    float4 nbt = { kkn.x * a4.x, kkn.y * a4.y, kkn.z * a4.z, kkn.w * a4.w };
    *(float4*)(a_buf + base) = nbt;

    float4 kf;
    kf.x = k0.x * (1.f + (a4.x - 1.f) * kac.x);
    kf.y = k0.y * (1.f + (a4.y - 1.f) * kac.y);
    kf.z = k0.z * (1.f + (a4.z - 1.f) * kac.z);
    kf.w = k0.w * (1.f + (a4.w - 1.f) * kac.w);
    *(float4*)(k_buf + base) = kf;

    float rk = r4.x * kf.x * rkc.x + r4.y * kf.y * rkc.y + r4.z * kf.z * rkc.z + r4.w * kf.w * rkc.w;
    rk += __shfl_xor(rk, 1); rk += __shfl_xor(rk, 2);
    rk += __shfl_xor(rk, 4); rk += __shfl_xor(rk, 8);
    if ((tid & 15) == 0) rk_sum[(size_t)tok * NH + (tid >> 4)] = rk;

    float4 vfin;
    vfin.x = v0.x + (vf.x - v0.x) * vg.x;
    vfin.y = v0.y + (vf.y - v0.y) * vg.y;
    vfin.z = v0.z + (vf.z - v0.z) * vg.z;
    vfin.w = v0.w + (vf.w - v0.w) * vg.w;
    *(float4*)(v_buf + base) = vfin;

    float4 wd;
    wd.x = __expf(DECAY_C * sigm(wl.x));
    wd.y = __expf(DECAY_C * sigm(wl.y));
    wd.z = __expf(DECAY_C * sigm(wl.z));
    wd.w = __expf(DECAY_C * sigm(wl.w));
    *(float4*)(wl_buf + base) = wd;
}

// ---------------- sequential scan, v5: 512-thread blocks, grid (64,2) ->
// 128 blocks, 8 waves each -> 2 waves/SIMD (TLP hides chain+LDS latency that
// held v2/v3 at ~129us with 1 wave/SIMD). vecJ staged once per 8 waves (half
// the redundant fetch). y in-register (row_sum16 off the s-chain + 4-lane
// coalesced store) -> ypart LDS deleted. a_buf carries precomputed kkn*a.
__global__ __launch_bounds__(512, 1)
void scan_kernel(const float* __restrict__ r_buf, const float* __restrict__ w_buf,
                 const float* __restrict__ k_buf, const float* __restrict__ kkn_buf,
                 const float* __restrict__ a_buf, const float* __restrict__ v_buf,
                 float* __restrict__ out_scan, float* __restrict__ state_out)
{
    __shared__ float vecJ[2][5][16][64];      // 40 KB
    __shared__ float vbuf2[2][16][32];        // 4 KB
    const int bh = blockIdx.x;
    const int rg = blockIdx.y;                // 0..1, 32 v-rows per block
    const int b = bh >> 4, h = bh & 15;
    const int tid = threadIdx.x;              // 0..511
    const int row = tid >> 4;                 // 0..31
    const int l16 = tid & 15;
    const int lofs = l16 * 4;
    const int rowbase = rg * 32;
    const size_t tok0 = ((size_t)b * 1024) * DD + h * HSZ;
    float s0 = 0.f, s1 = 0.f, s2 = 0.f, s3 = 0.f;

#define STAGE(cc, bb) do {                                                        \
    if (tid < 256) {                                                              \
        const int tt_ = tid >> 4;                                                 \
        const int dd4_ = (tid & 15) * 4;                                          \
        size_t gofs_ = tok0 + (size_t)((cc) * 16 + tt_) * DD + dd4_;              \
        float* db_ = &vecJ[bb][0][0][0] + ((tid >> 6) << 8);                      \
        __builtin_amdgcn_global_load_lds(GLB(r_buf + gofs_),   LDS(db_),        16, 0, 0); \
        __builtin_amdgcn_global_load_lds(GLB(w_buf + gofs_),   LDS(db_ + 1024), 16, 0, 0); \
        __builtin_amdgcn_global_load_lds(GLB(k_buf + gofs_),   LDS(db_ + 2048), 16, 0, 0); \
        __builtin_amdgcn_global_load_lds(GLB(kkn_buf + gofs_), LDS(db_ + 3072), 16, 0, 0); \
        __builtin_amdgcn_global_load_lds(GLB(a_buf + gofs_),   LDS(db_ + 4096), 16, 0, 0); \
    }                                                                             \
    if (tid < 128) {                                                              \
        size_t vofs_ = tok0 + (size_t)((cc) * 16 + (tid >> 3)) * DD + rowbase + (tid & 7) * 4; \
        float* vd_ = &vbuf2[bb][0][0] + ((tid >> 6) << 8);                        \
        __builtin_amdgcn_global_load_lds(GLB(v_buf + vofs_), LDS(vd_), 16, 0, 0); \
    }                                                                             \
} while (0)

#define LD_TOK(P, tt) do {                                                        \
    P##r = *(const float4*)(vb + (tt) * 64 + lofs);                               \
    P##w = *(const float4*)(vb + 1024 + (tt) * 64 + lofs);                        \
    P##k = *(const float4*)(vb + 2048 + (tt) * 64 + lofs);                        \
    P##q = *(const float4*)(vb + 3072 + (tt) * 64 + lofs);                        \
    P##a = *(const float4*)(vb + 4096 + (tt) * 64 + lofs);                        \
    P##v = vbp[(tt) * 32 + row];                                                  \
} while (0)

#define STEP(P, tt) do {                                                          \
    float sa_ = P##q.x * s0;                                                      \
    sa_ = fmaf(P##q.y, s1, sa_);                                                  \
    sa_ = fmaf(P##q.z, s2, sa_);                                                  \
    sa_ = fmaf(P##q.w, s3, sa_);                                                  \
    sa_ = row_sum16(sa_);                                                         \
    float b0_ = fmaf(s0, P##w.x, P##v * P##k.x);                                  \
    float b1_ = fmaf(s1, P##w.y, P##v * P##k.y);                                  \
    float b2_ = fmaf(s2, P##w.z, P##v * P##k.z);                                  \
    float b3_ = fmaf(s3, P##w.w, P##v * P##k.w);                                  \
    s0 = fmaf(sa_, -P##a.x, b0_);                                                 \
    s1 = fmaf(sa_, -P##a.y, b1_);                                                 \
    s2 = fmaf(sa_, -P##a.z, b2_);                                                 \
    s3 = fmaf(sa_, -P##a.w, b3_);                                                 \
    float y_ = P##r.x * s0;                                                       \
    y_ = fmaf(P##r.y, s1, y_);                                                    \
    y_ = fmaf(P##r.z, s2, y_);                                                    \
    y_ = fmaf(P##r.w, s3, y_);                                                    \
    y_ = row_sum16(y_);                                                           \
    if (l16 == 0)                                                                 \
        out_scan[tok0 + (size_t)((c) * 16 + (tt)) * DD + rowbase + row] = y_;     \
} while (0)

    STAGE(0, 0);
    __syncthreads();   // drains vmcnt -> chunk 0 resident

    for (int c = 0; c < 64; c++) {
        const int buf = c & 1;
        if (c < 63) STAGE(c + 1, buf ^ 1);   // in flight during the whole chunk
        const float* vb  = &vecJ[buf][0][0][0];
        const float* vbp = &vbuf2[buf][0][0];
        float4 Ar, Aw, Ak, Aq, Aa; float Av;
        float4 Br, Bw, Bk, Bq, Ba; float Bv;
        LD_TOK(A, 0);
#pragma unroll
        for (int tp = 0; tp < 8; tp++) {
            LD_TOK(B, 2 * tp + 1);
            STEP(A, 2 * tp);
            if (tp < 7) LD_TOK(A, 2 * tp + 2);
            STEP(B, 2 * tp + 1);
        }
        __syncthreads();   // drains staged loads for c+1
    }

#undef STAGE
#undef LD_TOK
#undef STEP

    float* so = state_out + ((size_t)(b * NH + h) * HSZ + rowbase + row) * HSZ + l16 * 4;
    float4 sv = {s0, s1, s2, s3};
    *(float4*)so = sv;
}

// ---------------- stage 2: GroupNorm + residual + gate -> z (plain bf16)
__global__ __launch_bounds__(256)
void elemwise2(const float* __restrict__ out_scan, const float* __restrict__ rk_sum,
               const float* __restrict__ v_buf, const float* __restrict__ g_buf,
               const float* __restrict__ gscale, const float* __restrict__ gbias,
               ushort* __restrict__ z_buf)
{
    const int tok = blockIdx.x;
    const int tid = threadIdx.x;
    const int d0 = tid * 4;
    const size_t base = (size_t)tok * DD + d0;

    float4 o = *(const float4*)(out_scan + base);
    float sm = o.x + o.y + o.z + o.w;
    float ss = o.x * o.x + o.y * o.y + o.z * o.z + o.w * o.w;
    sm += __shfl_xor(sm, 1); sm += __shfl_xor(sm, 2);
    sm += __shfl_xor(sm, 4); sm += __shfl_xor(sm, 8);
    ss += __shfl_xor(ss, 1); ss += __shfl_xor(ss, 2);
    ss += __shfl_xor(ss, 4); ss += __shfl_xor(ss, 8);
    float mu = sm * (1.f / 64.f);
    float var = ss * (1.f / 64.f) - mu * mu;
    float rs = rsqrtf(var + GN_EPS);
    float rk = rk_sum[(size_t)tok * NH + (tid >> 4)];

    float4 v4 = *(const float4*)(v_buf + base);
    float4 g4 = *(const float4*)(g_buf + base);
    float4 gs = *(const float4*)(gscale + d0);
    float4 gb = *(const float4*)(gbias + d0);
    ushort4 z;
    z.x = f2bf(((o.x - mu) * rs * gs.x + gb.x + rk * v4.x) * g4.x);
    z.y = f2bf(((o.y - mu) * rs * gs.y + gb.y + rk * v4.y) * g4.y);
    z.z = f2bf(((o.z - mu) * rs * gs.z + gb.z + rk * v4.z) * g4.z);
    z.w = f2bf(((o.w - mu) * rs * gs.w + gb.w + rk * v4.w) * g4.w);
    *(ushort4*)(z_buf + base) = z;
}

extern "C" void kernel_launch(void* const* d_in, const int* in_sizes, int n_in,
                              void* d_out, int out_size, void* d_ws, size_t ws_size,
                              hipStream_t stream) {
    const float* cur    = (const float*)d_in[0];
    const float* prev   = (const float*)d_in[1];
    const float* vfirst = (const float*)d_in[2];
    const float* rwkvag = (const float*)d_in[3];
    const float* rw_W   = (const float*)d_in[4];
    const float* w1     = (const float*)d_in[5];
    const float* w2     = (const float*)d_in[6];
    const float* w2_b   = (const float*)d_in[7];
    const float* kw_W   = (const float*)d_in[8];
    const float* vw_W   = (const float*)d_in[9];
    const float* a1     = (const float*)d_in[10];
    const float* a2     = (const float*)d_in[11];
    const float* a2_b   = (const float*)d_in[12];
    const float* v1     = (const float*)d_in[13];
    const float* v2     = (const float*)d_in[14];
    const float* v2_b   = (const float*)d_in[15];
    const float* g1     = (const float*)d_in[16];
    const float* g2     = (const float*)d_in[17];
    const float* g2_b   = (const float*)d_in[18];
    const float* k_k    = (const float*)d_in[19];
    const float* k_a    = (const float*)d_in[20];
    const float* r_k    = (const float*)d_in[21];
    const float* gn_s   = (const float*)d_in[22];
    const float* gn_b   = (const float*)d_in[23];
    const float* out_W  = (const float*)d_in[24];

    float* out = (float*)d_out;
    float* y_out = out;
    float* state_out = out + (size_t)NT * DD;
    float* vf_out = state_out + (size_t)4 * NH * HSZ * HSZ;

    // ---- workspace carve (float units).
    float* p = (float*)d_ws;
    const size_t big = (size_t)NT * DD;   // 4,194,304
    const size_t half = big / 2;          // 2,097,152
    float* r_buf = p;   p += big;
    float* k_buf = p;   p += big;   // k0 -> k final in place
    float* v_buf = p;   p += big;   // v0 -> v final in place
    // x-region: 6 branch pairs (hi,lo), each pair = 'big' floats = 16 MB
    float* xreg = p;
    ushort* xrh = (ushort*)(xreg);            ushort* xrl = (ushort*)(xreg + half);
    ushort* xwh = (ushort*)(xreg + 2*half);   ushort* xwl = (ushort*)(xreg + 3*half);
    ushort* xkh = (ushort*)(xreg + 4*half);   ushort* xkl = (ushort*)(xreg + 5*half);
    ushort* xvh = (ushort*)(xreg + 6*half);   ushort* xvl = (ushort*)(xreg + 7*half);
    ushort* xah = (ushort*)(xreg + 8*half);   ushort* xal = (ushort*)(xreg + 9*half);
    ushort* xgh = (ushort*)(xreg + 10*half);  ushort* xgl = (ushort*)(xreg + 11*half);
    p += 12 * half;
    // overlays (valid after gemm_mega1 completes):
    float* w_buf   = xreg + 0 * half;   // wl -> wdec in place (16 MB over xr pair)
    float* a_buf   = xreg + 2 * half;   // over xw pair (a -> kkn*a in e1)
    float* vg_buf  = xreg + 4 * half;   // over xk pair; reused as out_scan after E1
    float* os_buf  = vg_buf;
    float* g_buf   = xreg + 6 * half;   // over xv pair
    float* kkn_buf = xreg + 8 * half;   // over xa pair
    // Bt region: [3584][1024] bf16 hi + lo
    float* btreg = p;
    ushort* Bth = (ushort*)btreg;                      // 1,835,008 floats
    ushort* Btl = (ushort*)(btreg + 1835008);
    p += 2 * 1835008;
    // overlays on Bt region (valid after gemm_mega1):
    ushort* z_bf  = (ushort*)btreg;                    // 2,097,152 floats
    ushort* outTh = (ushort*)(btreg + 2097152);        // 524,288 floats
    // stage-2 transposed weights (hi/lo)
    ushort* w2Th = (ushort*)p; p += 32768; ushort* w2Tl = (ushort*)p; p += 32768;
    ushort* a2Th = (ushort*)p; p += 32768; ushort* a2Tl = (ushort*)p; p += 32768;
    ushort* v2Th = (ushort*)p; p += 16384; ushort* v2Tl = (ushort*)p; p += 16384;
    ushort* g2Th = (ushort*)p; p += 65536; ushort* g2Tl = (ushort*)p; p += 65536;
    // LoRA hidden buffers (hi/lo)
    ushort* hwh = (ushort*)p; p += 131072; ushort* hwl = (ushort*)p; p += 131072;
    ushort* hah = (ushort*)p; p += 131072; ushort* hal = (ushort*)p; p += 131072;
    ushort* hvh = (ushort*)p; p += 65536;  ushort* hvl = (ushort*)p; p += 65536;
    ushort* hgh = (ushort*)p; p += 262144; ushort* hgl = (ushort*)p; p += 262144;
    float* rks_buf = p;        p += 65536;

    dim3 blk(256);
    dim3 t32x8(32, 8);

    // ---- stage-1 B transposes into concatenated Bt [3584][1024]
    transpose_pad<<<dim3(32, 32), t32x8, 0, stream>>>(rw_W, Bth + (size_t)0 * 1024,    Btl + (size_t)0 * 1024,    1024, 1024);
    transpose_pad<<<dim3(32, 32), t32x8, 0, stream>>>(kw_W, Bth + (size_t)1024 * 1024, Btl + (size_t)1024 * 1024, 1024, 1024);
    transpose_pad<<<dim3(32, 32), t32x8, 0, stream>>>(vw_W, Bth + (size_t)2048 * 1024, Btl + (size_t)2048 * 1024, 1024, 1024);
    transpose_pad<<<dim3(4, 32), t32x8, 0, stream>>>(w1, Bth + (size_t)3072 * 1024, Btl + (size_t)3072 * 1024, 1024, 64);
    transpose_pad<<<dim3(4, 32), t32x8, 0, stream>>>(a1, Bth + (size_t)3200 * 1024, Btl + (size_t)3200 * 1024, 1024, 64);
    transpose_pad<<<dim3(4, 32), t32x8, 0, stream>>>(v1, Bth + (size_t)3328 * 1024, Btl + (size_t)3328 * 1024, 1024, 32);
    transpose_pad<<<dim3(4, 32), t32x8, 0, stream>>>(g1, Bth + (size_t)3456 * 1024, Btl + (size_t)3456 * 1024, 1024, 128);
    // stage-2 weights
    transpose_pad<<<dim3(32, 2), t32x8, 0, stream>>>(w2, w2Th, w2Tl, 64, 1024);
    transpose_pad<<<dim3(32, 2), t32x8, 0, stream>>>(a2, a2Th, a2Tl, 64, 1024);
    transpose_pad<<<dim3(32, 1), t32x8, 0, stream>>>(v2, v2Th, v2Tl, 32, 1024);
    transpose_pad<<<dim3(32, 4), t32x8, 0, stream>>>(g2, g2Th, g2Tl, 128, 1024);

    // ---- fused token-shift mixes (hi/lo) for all 6 branches
    mix6<<<NT, blk, 0, stream>>>(cur, prev, rwkvag,
                                 xrh, xrl, xwh, xwl, xkh, xkl,
                                 xvh, xvl, xah, xal, xgh, xgl);

    // ---- MEGA stage-1 GEMM (r,k,v + 4 LoRA stage-1), 128^2, counted-vmcnt dbuf
    gemm_mega1<<<dim3(32, 28), blk, 0, stream>>>(
        xrh, xrl, xwh, xwl, xkh, xkl, xvh, xvl, xah, xal, xgh, xgl,
        Bth, Btl, r_buf, k_buf, v_buf,
        hwh, hwl, hah, hal, hvh, hvl, hgh, hgl);

    // out_W transpose (Bt region is free from here on)
    transpose_pad<<<dim3(32, 32), t32x8, 0, stream>>>(out_W, outTh, nullptr, 1024, 1024);

    // ---- MEGA stage-2 GEMM (w2/a2/v2/g2), overwrites x-region overlays
    gemm_mega2<<<dim3(32, 32), blk, 0, stream>>>(
        hwh, hwl, hah, hal, hvh, hvl, hgh, hgl,
        w2Th, w2Tl, a2Th, a2Tl, v2Th, v2Tl, g2Th, g2Tl,
        w2_b, a2_b, v2_b, g2_b,
        w_buf, a_buf, vg_buf, g_buf);

    // ---- elementwise + scan + epilogue
    elemwise1<<<NT, blk, 0, stream>>>(r_buf, w_buf, k_buf, v_buf, kkn_buf, a_buf,
                                      vg_buf, vfirst, k_k, k_a, r_k, rks_buf);

    scan_kernel<<<dim3(64, 2), dim3(512), 0, stream>>>(r_buf, w_buf, k_buf, kkn_buf, a_buf, v_buf,
                                                       os_buf, state_out);

    elemwise2<<<NT, blk, 0, stream>>>(os_buf, rks_buf, v_buf, g_buf, gn_s, gn_b, z_bf);

    // ---- y = z @ out_W (plain bf16, counted-vmcnt dbuf)
    gemm_bf16s<<<dim3(32, 8), blk, 0, stream>>>(z_bf, outTh, y_out, 1024, 1024);

    // ---- v_first passthrough
    hipMemcpyAsync(vf_out, vfirst, (size_t)NT * DD * sizeof(float),
                   hipMemcpyDeviceToDevice, stream);
}

// Round 11
// 501.577 us; speedup vs baseline: 1.1076x; 1.1076x over previous
//
#include <hip/hip_runtime.h>
#include <math.h>

#define NT 4096      // B*T
#define DD 1024      // D == DM
#define NH 16
#define HSZ 64
#define GN_EPS 1e-5f
#define DECAY_C -0.606531f

typedef __attribute__((ext_vector_type(8))) short short8;
typedef __attribute__((ext_vector_type(4))) float float4v;

#define GLB(p) ((const __attribute__((address_space(1))) void*)(p))
#define LDS(p) ((__attribute__((address_space(3))) void*)(p))

#define MEMFENCE asm volatile("" ::: "memory")

__device__ __forceinline__ float sigm(float x) { return 1.f / (1.f + __expf(-x)); }

__device__ __forceinline__ unsigned short f2bf(float f) {
    unsigned int u = __float_as_uint(f);
    u = (u + 0x7fffu + ((u >> 16) & 1u)) >> 16;
    return (unsigned short)u;
}
__device__ __forceinline__ float bf2f(unsigned short h) {
    return __uint_as_float(((unsigned int)h) << 16);
}

// Full sum across each 16-lane row via DPP row_ror rotate-adds (VALU pipe only)
__device__ __forceinline__ float row_sum16(float x) {
    int t;
    t = __builtin_amdgcn_update_dpp(0, __float_as_int(x), 0x128, 0xF, 0xF, true); // ror 8
    x += __int_as_float(t);
    t = __builtin_amdgcn_update_dpp(0, __float_as_int(x), 0x124, 0xF, 0xF, true); // ror 4
    x += __int_as_float(t);
    t = __builtin_amdgcn_update_dpp(0, __float_as_int(x), 0x122, 0xF, 0xF, true); // ror 2
    x += __int_as_float(t);
    t = __builtin_amdgcn_update_dpp(0, __float_as_int(x), 0x121, 0xF, 0xF, true); // ror 1
    x += __int_as_float(t);
    return x;
}

// ---------------- fused 6-branch mix + hi/lo split-cast
__global__ __launch_bounds__(256)
void mix6(const float* __restrict__ cur, const float* __restrict__ prev,
          const float* __restrict__ lam,
          ushort* __restrict__ xrh, ushort* __restrict__ xrl,
          ushort* __restrict__ xwh, ushort* __restrict__ xwl,
          ushort* __restrict__ xkh, ushort* __restrict__ xkl,
          ushort* __restrict__ xvh, ushort* __restrict__ xvl,
          ushort* __restrict__ xah, ushort* __restrict__ xal,
          ushort* __restrict__ xgh, ushort* __restrict__ xgl)
{
    const int tok = blockIdx.x;
    const int d0 = threadIdx.x * 4;
    const size_t base = (size_t)tok * DD + d0;
    float4 c = *(const float4*)(cur + base);
    float4 p = *(const float4*)(prev + base);
    float dx = p.x - c.x, dy = p.y - c.y, dz = p.z - c.z, dw = p.w - c.w;
    ushort* hs[6] = {xrh, xwh, xkh, xvh, xah, xgh};
    ushort* ls[6] = {xrl, xwl, xkl, xvl, xal, xgl};
#pragma unroll
    for (int j = 0; j < 6; j++) {
        float4 l = *(const float4*)(lam + j * DD + d0);
        float m0 = c.x + l.x * dx;
        float m1 = c.y + l.y * dy;
        float m2 = c.z + l.z * dz;
        float m3 = c.w + l.w * dw;
        ushort4 h;
        h.x = f2bf(m0); h.y = f2bf(m1); h.z = f2bf(m2); h.w = f2bf(m3);
        *(ushort4*)(hs[j] + base) = h;
        ushort4 lo;
        lo.x = f2bf(m0 - bf2f(h.x));
        lo.y = f2bf(m1 - bf2f(h.y));
        lo.z = f2bf(m2 - bf2f(h.z));
        lo.w = f2bf(m3 - bf2f(h.w));
        *(ushort4*)(ls[j] + base) = lo;
    }
}

// ---------------- transpose + split-cast with zero-padding (single job):
// W[K][N] fp32 -> Wt[Npad][K] hi/lo bf16. grid.x covers Npad/32; cols >= N -> 0.
__global__ __launch_bounds__(256)
void transpose_pad(const float* __restrict__ W, ushort* __restrict__ Wh,
                   ushort* __restrict__ Wl, int K, int N)
{
    __shared__ float tile[32][33];
    const int bx = blockIdx.x * 32;  // N (padded)
    const int by = blockIdx.y * 32;  // K
    const int tx = threadIdx.x, ty = threadIdx.y;  // 32 x 8
#pragma unroll
    for (int i = 0; i < 32; i += 8) {
        float v = 0.f;
        if (bx + tx < N) v = W[(size_t)(by + ty + i) * N + bx + tx];
        tile[ty + i][tx] = v;
    }
    __syncthreads();
#pragma unroll
    for (int i = 0; i < 32; i += 8) {
        float v = tile[tx][ty + i];
        ushort h = f2bf(v);
        size_t o = (size_t)(bx + ty + i) * K + by + tx;
        Wh[o] = h;
        if (Wl) Wl[o] = f2bf(v - bf2f(h));
    }
}

// ---------------- batched transpose: 11 jobs in ONE dispatch (saves ~10
// launch gaps). Job table passed by value; flat blockIdx.x -> (job, tile).
struct TJob { const float* W; ushort* Wh; ushort* Wl; int K, N, nx, cnt; };
struct TJobs { TJob j[11]; };

__global__ __launch_bounds__(256)
void transpose_all(TJobs jobs)
{
    __shared__ float tile[32][33];
    int rem = blockIdx.x;
    int ji = 0;
    while (ji < 10 && rem >= jobs.j[ji].cnt) { rem -= jobs.j[ji].cnt; ji++; }
    const float* W = jobs.j[ji].W;
    ushort* Wh = jobs.j[ji].Wh;
    ushort* Wl = jobs.j[ji].Wl;
    const int K = jobs.j[ji].K, N = jobs.j[ji].N, nx = jobs.j[ji].nx;
    const int bx = (rem % nx) * 32;
    const int by = (rem / nx) * 32;
    const int tx = threadIdx.x, ty = threadIdx.y;  // 32 x 8
#pragma unroll
    for (int i = 0; i < 32; i += 8) {
        float v = 0.f;
        if (bx + tx < N) v = W[(size_t)(by + ty + i) * N + bx + tx];
        tile[ty + i][tx] = v;
    }
    __syncthreads();
#pragma unroll
    for (int i = 0; i < 32; i += 8) {
        float v = tile[tx][ty + i];
        ushort h = f2bf(v);
        size_t o = (size_t)(bx + ty + i) * K + by + tx;
        Wh[o] = h;
        Wl[o] = f2bf(v - bf2f(h));
    }
}

// LDS chunk swizzle: row-dependent XOR on the 16B-chunk index.
// bank-group g = (row*4 + chunk) % 8; chunk = quad ^ ((row>>1)&3) spreads each
// 16-lane quarter-wave over all 8 groups (2 lanes each -> free).
#define SWZ(r) (((r) >> 1) & 3)

// ---------------- MEGA stage-1 GEMM: 128x128 tiles, double-buffered with
// COUNTED vmcnt + raw barriers (T4): no vmcnt(0) drain in the main loop.
// N = 3584 = r[0,1024) k[1024,2048) v[2048,3072) w1@3072(64) a1@3200(64)
//            v1@3328(32) g1@3456(128). K=1024, bf16x3 split, per-colblock A.
__global__ __launch_bounds__(256)
void gemm_mega1(const ushort* __restrict__ xrh, const ushort* __restrict__ xrl,
                const ushort* __restrict__ xwh, const ushort* __restrict__ xwl,
                const ushort* __restrict__ xkh, const ushort* __restrict__ xkl,
                const ushort* __restrict__ xvh, const ushort* __restrict__ xvl,
                const ushort* __restrict__ xah, const ushort* __restrict__ xal,
                const ushort* __restrict__ xgh, const ushort* __restrict__ xgl,
                const ushort* __restrict__ Bth, const ushort* __restrict__ Btl,
                float* __restrict__ r_buf, float* __restrict__ k_buf,
                float* __restrict__ v_buf,
                ushort* __restrict__ hwh, ushort* __restrict__ hwl,
                ushort* __restrict__ hah, ushort* __restrict__ hal,
                ushort* __restrict__ hvh, ushort* __restrict__ hvl,
                ushort* __restrict__ hgh, ushort* __restrict__ hgl)
{
    __shared__ ushort As[2][2][128 * 32];   // [dbuf][hi/lo]  32 KB
    __shared__ ushort Bs[2][2][128 * 32];   // 32 KB
    const int cb = blockIdx.y;
    const ushort* Ah; const ushort* Al;
    if (cb < 8)       { Ah = xrh; Al = xrl; }
    else if (cb < 16) { Ah = xkh; Al = xkl; }
    else if (cb < 24) { Ah = xvh; Al = xvl; }
    else if (cb == 24){ Ah = xwh; Al = xwl; }
    else if (cb == 25){ Ah = xah; Al = xal; }
    else if (cb == 26){ Ah = xvh; Al = xvl; }
    else              { Ah = xgh; Al = xgl; }

    const int tid = threadIdx.x;
    const int rowBase = blockIdx.x * 128;
    const int colBase = cb * 128;
    const int lane = tid & 63;
    const int wave = tid >> 6;
    const int wm = wave >> 1, wn = wave & 1;
    const int m15 = lane & 15, quad = lane >> 4;

    float4v zero4 = {0.f, 0.f, 0.f, 0.f};
    float4v acc[4][4];
#pragma unroll
    for (int i = 0; i < 4; i++)
#pragma unroll
        for (int j = 0; j < 4; j++) acc[i][j] = zero4;

#define STAGE1(kk, bb) do {                                                       \
    const int k0_ = (kk) * 32;                                                    \
    _Pragma("unroll")                                                             \
    for (int i_ = 0; i_ < 2; i_++) {                                              \
        int idx_ = i_ * 256 + tid;                                                \
        int r_ = idx_ >> 2, seg_ = idx_ & 3;                                      \
        int sg_ = seg_ ^ SWZ(r_);   /* pre-swizzled source; LDS dest linear */    \
        size_t aoff_ = (size_t)(rowBase + r_) * 1024 + k0_ + sg_ * 8;             \
        size_t boff_ = (size_t)(colBase + r_) * 1024 + k0_ + sg_ * 8;             \
        int dst_ = (i_ * 256 + (tid & ~63)) * 8;                                  \
        __builtin_amdgcn_global_load_lds(GLB(Ah + aoff_),  LDS(&As[bb][0][0] + dst_), 16, 0, 0); \
        __builtin_amdgcn_global_load_lds(GLB(Al + aoff_),  LDS(&As[bb][1][0] + dst_), 16, 0, 0); \
        __builtin_amdgcn_global_load_lds(GLB(Bth + boff_), LDS(&Bs[bb][0][0] + dst_), 16, 0, 0); \
        __builtin_amdgcn_global_load_lds(GLB(Btl + boff_), LDS(&Bs[bb][1][0] + dst_), 16, 0, 0); \
    }                                                                             \
} while (0)

    STAGE1(0, 0);                       // 8 loads -> buf0
    STAGE1(1, 1);                       // 8 loads -> buf1 (16 outstanding)
    asm volatile("s_waitcnt vmcnt(8)" ::: "memory");   // buf0 landed
    __builtin_amdgcn_s_barrier();
    MEMFENCE;

    for (int kt = 0; kt < 32; kt++) {
        const int buf = kt & 1;

        short8 ah[4], bh[4], al[4], bl[4];
#pragma unroll
        for (int mi = 0; mi < 4; mi++) {
            int ra = wm * 64 + mi * 16 + m15;
            int cs = (quad ^ SWZ(ra)) * 8;
            ah[mi] = *(const short8*)(&As[buf][0][0] + ra * 32 + cs);
            al[mi] = *(const short8*)(&As[buf][1][0] + ra * 32 + cs);
        }
#pragma unroll
        for (int ni = 0; ni < 4; ni++) {
            int rb = wn * 64 + ni * 16 + m15;
            int cs = (quad ^ SWZ(rb)) * 8;
            bh[ni] = *(const short8*)(&Bs[buf][0][0] + rb * 32 + cs);
            bl[ni] = *(const short8*)(&Bs[buf][1][0] + rb * 32 + cs);
        }
#pragma unroll
        for (int mi = 0; mi < 4; mi++)
#pragma unroll
            for (int ni = 0; ni < 4; ni++) {
                acc[mi][ni] = __builtin_amdgcn_mfma_f32_16x16x32_bf16(al[mi], bh[ni], acc[mi][ni], 0, 0, 0);
                acc[mi][ni] = __builtin_amdgcn_mfma_f32_16x16x32_bf16(ah[mi], bl[ni], acc[mi][ni], 0, 0, 0);
                acc[mi][ni] = __builtin_amdgcn_mfma_f32_16x16x32_bf16(ah[mi], bh[ni], acc[mi][ni], 0, 0, 0);
            }

        if (kt == 31) break;

        MEMFENCE;
        __builtin_amdgcn_s_barrier();   // all waves done reading buf[kt]
        MEMFENCE;
        if (kt < 30) {
            STAGE1(kt + 2, buf);        // refill the buffer just read
            asm volatile("s_waitcnt vmcnt(8)" ::: "memory");  // stage(kt+1) landed
        } else {
            asm volatile("s_waitcnt vmcnt(0)" ::: "memory");  // stage(31) landed
        }
        __builtin_amdgcn_s_barrier();   // buf[kt+1] ready for everyone
        MEMFENCE;
    }
#undef STAGE1

#pragma unroll
    for (int mi = 0; mi < 4; mi++) {
#pragma unroll
        for (int ni = 0; ni < 4; ni++) {
            int c = wn * 64 + ni * 16 + m15;   // col within 128-tile
#pragma unroll
            for (int rr = 0; rr < 4; rr++) {
                int row = rowBase + wm * 64 + mi * 16 + quad * 4 + rr;
                float v = acc[mi][ni][rr];
                if (cb < 24) {
                    float* dst = (cb < 8) ? r_buf : (cb < 16) ? k_buf : v_buf;
                    int n = (cb & 7) * 128 + c;
                    dst[(size_t)row * 1024 + n] = v;
                } else if (cb == 24) {
                    if (c < 64) {
                        float t = tanhf(v);
                        ushort h = f2bf(t);
                        hwh[(size_t)row * 64 + c] = h;
                        hwl[(size_t)row * 64 + c] = f2bf(t - bf2f(h));
                    }
                } else if (cb == 25) {
                    if (c < 64) {
                        ushort h = f2bf(v);
                        hah[(size_t)row * 64 + c] = h;
                        hal[(size_t)row * 64 + c] = f2bf(v - bf2f(h));
                    }
                } else if (cb == 26) {
                    if (c < 32) {
                        ushort h = f2bf(v);
                        hvh[(size_t)row * 32 + c] = h;
                        hvl[(size_t)row * 32 + c] = f2bf(v - bf2f(h));
                    }
                } else {
                    float t = sigm(v);
                    ushort h = f2bf(t);
                    hgh[(size_t)row * 128 + c] = h;
                    hgl[(size_t)row * 128 + c] = f2bf(t - bf2f(h));
                }
            }
        }
    }
}

// ---------------- MEGA stage-2 GEMM: 4 LoRA stage-2 products in one dispatch.
// blockIdx.y: 0-7 w2(K=64,none), 8-15 a2(K=64,sigm), 16-23 v2(K=32,sigm),
// 24-31 g2(K=128,none). All outputs fp32 [4096][1024].
__global__ __launch_bounds__(256)
void gemm_mega2(const ushort* __restrict__ hwh, const ushort* __restrict__ hwl,
                const ushort* __restrict__ hah, const ushort* __restrict__ hal,
                const ushort* __restrict__ hvh, const ushort* __restrict__ hvl,
                const ushort* __restrict__ hgh, const ushort* __restrict__ hgl,
                const ushort* __restrict__ w2Th, const ushort* __restrict__ w2Tl,
                const ushort* __restrict__ a2Th, const ushort* __restrict__ a2Tl,
                const ushort* __restrict__ v2Th, const ushort* __restrict__ v2Tl,
                const ushort* __restrict__ g2Th, const ushort* __restrict__ g2Tl,
                const float* __restrict__ w2_b, const float* __restrict__ a2_b,
                const float* __restrict__ v2_b, const float* __restrict__ g2_b,
                float* __restrict__ w_buf, float* __restrict__ a_buf,
                float* __restrict__ vg_buf, float* __restrict__ g_buf)
{
    __shared__ ushort AsH[128 * 32];
    __shared__ ushort BsH[128 * 32];
    __shared__ ushort AsL[128 * 32];
    __shared__ ushort BsL[128 * 32];
    const int cb = blockIdx.y;
    const int seg = cb >> 3;
    const int K = (seg == 2) ? 32 : (seg == 3) ? 128 : 64;
    const ushort *Ah, *Al, *Bh, *Bl;
    const float* bias;
    float* outp;
    if (seg == 0) { Ah = hwh; Al = hwl; Bh = w2Th; Bl = w2Tl; bias = w2_b; outp = w_buf; }
    else if (seg == 1) { Ah = hah; Al = hal; Bh = a2Th; Bl = a2Tl; bias = a2_b; outp = a_buf; }
    else if (seg == 2) { Ah = hvh; Al = hvl; Bh = v2Th; Bl = v2Tl; bias = v2_b; outp = vg_buf; }
    else { Ah = hgh; Al = hgl; Bh = g2Th; Bl = g2Tl; bias = g2_b; outp = g_buf; }

    const int tid = threadIdx.x;
    const int rowBase = blockIdx.x * 128;
    const int colBase = (cb & 7) * 128;
    const int lane = tid & 63;
    const int wave = tid >> 6;
    const int wm = wave >> 1, wn = wave & 1;
    const int m15 = lane & 15, quad = lane >> 4;

    float4v zero4 = {0.f, 0.f, 0.f, 0.f};
    float4v acc[4][4];
#pragma unroll
    for (int i = 0; i < 4; i++)
#pragma unroll
        for (int j = 0; j < 4; j++) acc[i][j] = zero4;

    for (int k0 = 0; k0 < K; k0 += 32) {
#pragma unroll
        for (int i = 0; i < 2; i++) {
            int idx = i * 256 + tid;
            int r = idx >> 2, s8 = idx & 3;
            int sg = s8 ^ SWZ(r);   // pre-swizzled source, linear LDS dest
            size_t aoff = (size_t)(rowBase + r) * K + k0 + sg * 8;
            size_t boff = (size_t)(colBase + r) * K + k0 + sg * 8;
            int dst = (i * 256 + (tid & ~63)) * 8;
            __builtin_amdgcn_global_load_lds(GLB(Ah + aoff), LDS(AsH + dst), 16, 0, 0);
            __builtin_amdgcn_global_load_lds(GLB(Bh + boff), LDS(BsH + dst), 16, 0, 0);
            __builtin_amdgcn_global_load_lds(GLB(Al + aoff), LDS(AsL + dst), 16, 0, 0);
            __builtin_amdgcn_global_load_lds(GLB(Bl + boff), LDS(BsL + dst), 16, 0, 0);
        }
        __syncthreads();
        short8 ah[4], bh[4], al[4], bl[4];
#pragma unroll
        for (int mi = 0; mi < 4; mi++) {
            int ra = wm * 64 + mi * 16 + m15;
            int cs = (quad ^ SWZ(ra)) * 8;
            ah[mi] = *(const short8*)(AsH + ra * 32 + cs);
            al[mi] = *(const short8*)(AsL + ra * 32 + cs);
        }
#pragma unroll
        for (int ni = 0; ni < 4; ni++) {
            int rb = wn * 64 + ni * 16 + m15;
            int cs = (quad ^ SWZ(rb)) * 8;
            bh[ni] = *(const short8*)(BsH + rb * 32 + cs);
            bl[ni] = *(const short8*)(BsL + rb * 32 + cs);
        }
#pragma unroll
        for (int mi = 0; mi < 4; mi++)
#pragma unroll
            for (int ni = 0; ni < 4; ni++) {
                acc[mi][ni] = __builtin_amdgcn_mfma_f32_16x16x32_bf16(al[mi], bh[ni], acc[mi][ni], 0, 0, 0);
                acc[mi][ni] = __builtin_amdgcn_mfma_f32_16x16x32_bf16(ah[mi], bl[ni], acc[mi][ni], 0, 0, 0);
                acc[mi][ni] = __builtin_amdgcn_mfma_f32_16x16x32_bf16(ah[mi], bh[ni], acc[mi][ni], 0, 0, 0);
            }
        __syncthreads();
    }

#pragma unroll
    for (int mi = 0; mi < 4; mi++) {
#pragma unroll
        for (int ni = 0; ni < 4; ni++) {
            int col = colBase + wn * 64 + ni * 16 + m15;
            float bv = bias[col];
#pragma unroll
            for (int rr = 0; rr < 4; rr++) {
                int row = rowBase + wm * 64 + mi * 16 + quad * 4 + rr;
                float v = acc[mi][ni][rr] + bv;
                if (seg == 1 || seg == 2) v = sigm(v);
                outp[(size_t)row * 1024 + col] = v;
            }
        }
    }
}

// ---------------- plain bf16 GEMM (final out-projection), double-buffered
__global__ __launch_bounds__(256)
void gemm_bf16s(const ushort* __restrict__ Ah, const ushort* __restrict__ Bh,
                float* __restrict__ outF, int N, int K)
{
    __shared__ ushort As2[2][128 * 32];
    __shared__ ushort Bs2[2][128 * 32];
    const int tid = threadIdx.x;
    const int rowBase = blockIdx.x * 128;
    const int colBase = blockIdx.y * 128;
    const int lane = tid & 63;
    const int wave = tid >> 6;
    const int wm = wave >> 1, wn = wave & 1;
    const int m15 = lane & 15, quad = lane >> 4;

    float4v zero4 = {0.f, 0.f, 0.f, 0.f};
    float4v acc[4][4];
#pragma unroll
    for (int i = 0; i < 4; i++)
#pragma unroll
        for (int j = 0; j < 4; j++) acc[i][j] = zero4;

#define STAGE3(kk, bb) do {                                                       \
    const int k0_ = (kk) * 32;                                                    \
    _Pragma("unroll")                                                             \
    for (int i_ = 0; i_ < 2; i_++) {                                              \
        int idx_ = i_ * 256 + tid;                                                \
        int r_ = idx_ >> 2, seg_ = idx_ & 3;                                      \
        int sg_ = seg_ ^ SWZ(r_);                                                 \
        size_t aoff_ = (size_t)(rowBase + r_) * K + k0_ + sg_ * 8;                \
        size_t boff_ = (size_t)(colBase + r_) * K + k0_ + sg_ * 8;                \
        int dst_ = (i_ * 256 + (tid & ~63)) * 8;                                  \
        __builtin_amdgcn_global_load_lds(GLB(Ah + aoff_), LDS(&As2[bb][0] + dst_), 16, 0, 0); \
        __builtin_amdgcn_global_load_lds(GLB(Bh + boff_), LDS(&Bs2[bb][0] + dst_), 16, 0, 0); \
    }                                                                             \
} while (0)

    const int nk = K >> 5;
    STAGE3(0, 0);
    __syncthreads();

    for (int kt = 0; kt < nk; kt++) {
        const int buf = kt & 1;
        if (kt < nk - 1) STAGE3(kt + 1, buf ^ 1);
        short8 ah[4], bh[4];
#pragma unroll
        for (int mi = 0; mi < 4; mi++) {
            int ra = wm * 64 + mi * 16 + m15;
            ah[mi] = *(const short8*)(&As2[buf][0] + ra * 32 + (quad ^ SWZ(ra)) * 8);
        }
#pragma unroll
        for (int ni = 0; ni < 4; ni++) {
            int rb = wn * 64 + ni * 16 + m15;
            bh[ni] = *(const short8*)(&Bs2[buf][0] + rb * 32 + (quad ^ SWZ(rb)) * 8);
        }
#pragma unroll
        for (int mi = 0; mi < 4; mi++)
#pragma unroll
            for (int ni = 0; ni < 4; ni++)
                acc[mi][ni] = __builtin_amdgcn_mfma_f32_16x16x32_bf16(ah[mi], bh[ni], acc[mi][ni], 0, 0, 0);
        __syncthreads();
    }
#undef STAGE3

#pragma unroll
    for (int mi = 0; mi < 4; mi++) {
#pragma unroll
        for (int ni = 0; ni < 4; ni++) {
            int col = colBase + wn * 64 + ni * 16 + m15;
#pragma unroll
            for (int rr = 0; rr < 4; rr++) {
                int row = rowBase + wm * 64 + mi * 16 + quad * 4 + rr;
                outF[(size_t)row * N + col] = acc[mi][ni][rr];
            }
        }
    }
}

// ---------------- elementwise stage 1 (fp32)
__global__ __launch_bounds__(256)
void elemwise1(const float* __restrict__ r_buf, float* __restrict__ wl_buf,
               float* __restrict__ k_buf, float* __restrict__ v_buf,
               float* __restrict__ kkn_buf, const float* __restrict__ a_buf,
               const float* __restrict__ vg_buf, const float* __restrict__ vfirst,
               const float* __restrict__ kkw, const float* __restrict__ kaw,
               const float* __restrict__ rkw, float* __restrict__ rk_sum)
{
    const int tok = blockIdx.x;
    const int tid = threadIdx.x;
    const int d0 = tid * 4;
    const size_t base = (size_t)tok * DD + d0;

    float4 k0 = *(const float4*)(k_buf + base);
    float4 a4 = *(const float4*)(a_buf + base);
    float4 wl = *(const float4*)(wl_buf + base);
    float4 v0 = *(const float4*)(v_buf + base);
    float4 vg = *(const float4*)(vg_buf + base);
    float4 vf = *(const float4*)(vfirst + base);
    float4 r4 = *(const float4*)(r_buf + base);
    float4 kkc = *(const float4*)(kkw + d0);
    float4 kac = *(const float4*)(kaw + d0);
    float4 rkc = *(const float4*)(rkw + d0);

    float kk0 = k0.x * kkc.x, kk1 = k0.y * kkc.y, kk2 = k0.z * kkc.z, kk3 = k0.w * kkc.w;
    float ss = kk0 * kk0 + kk1 * kk1 + kk2 * kk2 + kk3 * kk3;
    ss += __shfl_xor(ss, 1); ss += __shfl_xor(ss, 2);
    ss += __shfl_xor(ss, 4); ss += __shfl_xor(ss, 8);
    float rn = rsqrtf(ss);
    float4 kkn = { kk0 * rn, kk1 * rn, kk2 * rn, kk3 * rn };
    *(float4*)(kkn_buf + base) = kkn;

    float4 kf;
    kf.x = k0.x * (1.f + (a4.x - 1.f) * kac.x);
    kf.y = k0.y * (1.f + (a4.y - 1.f) * kac.y);
    kf.z = k0.z * (1.f + (a4.z - 1.f) * kac.z);
    kf.w = k0.w * (1.f + (a4.w - 1.f) * kac.w);
    *(float4*)(k_buf + base) = kf;

    float rk = r4.x * kf.x * rkc.x + r4.y * kf.y * rkc.y + r4.z * kf.z * rkc.z + r4.w * kf.w * rkc.w;
    rk += __shfl_xor(rk, 1); rk += __shfl_xor(rk, 2);
    rk += __shfl_xor(rk, 4); rk += __shfl_xor(rk, 8);
    if ((tid & 15) == 0) rk_sum[(size_t)tok * NH + (tid >> 4)] = rk;

    float4 vfin;
    vfin.x = v0.x + (vf.x - v0.x) * vg.x;
    vfin.y = v0.y + (vf.y - v0.y) * vg.y;
    vfin.z = v0.z + (vf.z - v0.z) * vg.z;
    vfin.w = v0.w + (vf.w - v0.w) * vg.w;
    *(float4*)(v_buf + base) = vfin;

    float4 wd;
    wd.x = __expf(DECAY_C * sigm(wl.x));
    wd.y = __expf(DECAY_C * sigm(wl.y));
    wd.z = __expf(DECAY_C * sigm(wl.z));
    wd.w = __expf(DECAY_C * sigm(wl.w));
    *(float4*)(wl_buf + base) = wd;
}

// ---------------- sequential scan (round-8 best: v3 depth-4 + ypart pad 20,
// measured 128.2 us; ~128 us is this serial formulation's floor)
__global__ __launch_bounds__(256, 1)
void scan_kernel(const float* __restrict__ r_buf, const float* __restrict__ w_buf,
                 const float* __restrict__ k_buf, const float* __restrict__ kkn_buf,
                 const float* __restrict__ a_buf, const float* __restrict__ v_buf,
                 float* __restrict__ out_scan, float* __restrict__ state_out)
{
    __shared__ float vecJ[2][5][16][64];      // 40 KB
    __shared__ float vbuf2[2][16][16];        // 2 KB
    __shared__ float ypart[2][16][16][20];    // 40 KB  [buf][t][vrow][l16(pad 20)]
    const int bh = blockIdx.x;
    const int rg = blockIdx.y;
    const int b = bh >> 4, h = bh & 15;
    const int tid = threadIdx.x;
    const int row = tid >> 4, l16 = tid & 15;
    const int lofs = l16 * 4;
    const int rowbase = rg * 16;
    const size_t tok0 = ((size_t)b * 1024) * DD + h * HSZ;
    float s0 = 0.f, s1 = 0.f, s2 = 0.f, s3 = 0.f;

#define STAGE(cc, bb) do {                                                        \
    const int tt_ = tid >> 4;                                                     \
    const int dd4_ = (tid & 15) * 4;                                              \
    size_t gofs_ = tok0 + (size_t)((cc) * 16 + tt_) * DD + dd4_;                  \
    float* db_ = &vecJ[bb][0][0][0] + ((tid >> 6) << 8);                          \
    __builtin_amdgcn_global_load_lds(GLB(r_buf + gofs_),   LDS(db_),        16, 0, 0); \
    __builtin_amdgcn_global_load_lds(GLB(w_buf + gofs_),   LDS(db_ + 1024), 16, 0, 0); \
    __builtin_amdgcn_global_load_lds(GLB(k_buf + gofs_),   LDS(db_ + 2048), 16, 0, 0); \
    __builtin_amdgcn_global_load_lds(GLB(kkn_buf + gofs_), LDS(db_ + 3072), 16, 0, 0); \
    __builtin_amdgcn_global_load_lds(GLB(a_buf + gofs_),   LDS(db_ + 4096), 16, 0, 0); \
    if (tid < 64) {                                                               \
        size_t vofs_ = tok0 + (size_t)((cc) * 16 + (tid >> 2)) * DD + rowbase + (tid & 3) * 4; \
        __builtin_amdgcn_global_load_lds(GLB(v_buf + vofs_), LDS(&vbuf2[bb][0][0]), 16, 0, 0); \
    }                                                                             \
} while (0)

#define LD_TOK(P, tt) do {                                                        \
    P##r = *(const float4*)(vb + (tt) * 64 + lofs);                               \
    P##w = *(const float4*)(vb + 1024 + (tt) * 64 + lofs);                        \
    P##k = *(const float4*)(vb + 2048 + (tt) * 64 + lofs);                        \
    P##q = *(const float4*)(vb + 3072 + (tt) * 64 + lofs);                        \
    P##a = *(const float4*)(vb + 4096 + (tt) * 64 + lofs);                        \
    P##v = vbp[(tt) * 16 + row];                                                  \
} while (0)

#define STEP(P, tt) do {                                                          \
    float sa_ = P##q.x * s0;                                                      \
    sa_ = fmaf(P##q.y, s1, sa_);                                                  \
    sa_ = fmaf(P##q.z, s2, sa_);                                                  \
    sa_ = fmaf(P##q.w, s3, sa_);                                                  \
    sa_ = row_sum16(sa_);                                                         \
    float n0_ = P##q.x * P##a.x, n1_ = P##q.y * P##a.y;                           \
    float n2_ = P##q.z * P##a.z, n3_ = P##q.w * P##a.w;                           \
    float b0_ = fmaf(s0, P##w.x, P##v * P##k.x);                                  \
    float b1_ = fmaf(s1, P##w.y, P##v * P##k.y);                                  \
    float b2_ = fmaf(s2, P##w.z, P##v * P##k.z);                                  \
    float b3_ = fmaf(s3, P##w.w, P##v * P##k.w);                                  \
    s0 = fmaf(sa_, -n0_, b0_);                                                    \
    s1 = fmaf(sa_, -n1_, b1_);                                                    \
    s2 = fmaf(sa_, -n2_, b2_);                                                    \
    s3 = fmaf(sa_, -n3_, b3_);                                                    \
    float yp_ = P##r.x * s0;                                                      \
    yp_ = fmaf(P##r.y, s1, yp_);                                                  \
    yp_ = fmaf(P##r.z, s2, yp_);                                                  \
    yp_ = fmaf(P##r.w, s3, yp_);                                                  \
    ypart[buf][tt][row][l16] = yp_;                                               \
} while (0)

    STAGE(0, 0);
    __syncthreads();   // drains vmcnt -> chunk 0 resident

    for (int c = 0; c < 64; c++) {
        const int buf = c & 1;
        if (c < 63) STAGE(c + 1, buf ^ 1);   // in flight during the whole chunk
        const float* vb  = &vecJ[buf][0][0][0];
        const float* vbp = &vbuf2[buf][0][0];
        float4 Ar, Aw, Ak, Aq, Aa; float Av;
        float4 Br, Bw, Bk, Bq, Ba; float Bv;
        float4 Cr, Cw, Ck, Cq, Ca; float Cv;
        float4 Dr, Dw, Dk, Dq, Da; float Dv;
        LD_TOK(A, 0); LD_TOK(B, 1); LD_TOK(C, 2);
#pragma unroll
        for (int i4 = 0; i4 < 4; i4++) {
            LD_TOK(D, 4 * i4 + 3);
            STEP(A, 4 * i4);
            if (4 * i4 + 4 < 16) LD_TOK(A, 4 * i4 + 4);
            STEP(B, 4 * i4 + 1);
            if (4 * i4 + 5 < 16) LD_TOK(B, 4 * i4 + 5);
            STEP(C, 4 * i4 + 2);
            if (4 * i4 + 6 < 16) LD_TOK(C, 4 * i4 + 6);
            STEP(D, 4 * i4 + 3);
        }
        __syncthreads();  // ypart complete; also drains staged loads for c+1
        {
            const int t_ = tid >> 4, r_ = tid & 15;
            const float* yp = &ypart[buf][t_][r_][0];
            float4 y0 = *(const float4*)(yp);
            float4 y1 = *(const float4*)(yp + 4);
            float4 y2 = *(const float4*)(yp + 8);
            float4 y3 = *(const float4*)(yp + 12);
            float ys = ((y0.x + y0.y) + (y0.z + y0.w)) + ((y1.x + y1.y) + (y1.z + y1.w))
                     + ((y2.x + y2.y) + (y2.z + y2.w)) + ((y3.x + y3.y) + (y3.z + y3.w));
            out_scan[tok0 + (size_t)(c * 16 + t_) * DD + rowbase + r_] = ys;
        }
    }

#undef STAGE
#undef LD_TOK
#undef STEP

    float* so = state_out + ((size_t)(b * NH + h) * HSZ + rowbase + row) * HSZ + l16 * 4;
    float4 sv = {s0, s1, s2, s3};
    *(float4*)so = sv;
}

// ---------------- stage 2: GroupNorm + residual + gate -> z (plain bf16)
__global__ __launch_bounds__(256)
void elemwise2(const float* __restrict__ out_scan, const float* __restrict__ rk_sum,
               const float* __restrict__ v_buf, const float* __restrict__ g_buf,
               const float* __restrict__ gscale, const float* __restrict__ gbias,
               ushort* __restrict__ z_buf)
{
    const int tok = blockIdx.x;
    const int tid = threadIdx.x;
    const int d0 = tid * 4;
    const size_t base = (size_t)tok * DD + d0;

    float4 o = *(const float4*)(out_scan + base);
    float sm = o.x + o.y + o.z + o.w;
    float ss = o.x * o.x + o.y * o.y + o.z * o.z + o.w * o.w;
    sm += __shfl_xor(sm, 1); sm += __shfl_xor(sm, 2);
    sm += __shfl_xor(sm, 4); sm += __shfl_xor(sm, 8);
    ss += __shfl_xor(ss, 1); ss += __shfl_xor(ss, 2);
    ss += __shfl_xor(ss, 4); ss += __shfl_xor(ss, 8);
    float mu = sm * (1.f / 64.f);
    float var = ss * (1.f / 64.f) - mu * mu;
    float rs = rsqrtf(var + GN_EPS);
    float rk = rk_sum[(size_t)tok * NH + (tid >> 4)];

    float4 v4 = *(const float4*)(v_buf + base);
    float4 g4 = *(const float4*)(g_buf + base);
    float4 gs = *(const float4*)(gscale + d0);
    float4 gb = *(const float4*)(gbias + d0);
    ushort4 z;
    z.x = f2bf(((o.x - mu) * rs * gs.x + gb.x + rk * v4.x) * g4.x);
    z.y = f2bf(((o.y - mu) * rs * gs.y + gb.y + rk * v4.y) * g4.y);
    z.z = f2bf(((o.z - mu) * rs * gs.z + gb.z + rk * v4.z) * g4.z);
    z.w = f2bf(((o.w - mu) * rs * gs.w + gb.w + rk * v4.w) * g4.w);
    *(ushort4*)(z_buf + base) = z;
}

extern "C" void kernel_launch(void* const* d_in, const int* in_sizes, int n_in,
                              void* d_out, int out_size, void* d_ws, size_t ws_size,
                              hipStream_t stream) {
    const float* cur    = (const float*)d_in[0];
    const float* prev   = (const float*)d_in[1];
    const float* vfirst = (const float*)d_in[2];
    const float* rwkvag = (const float*)d_in[3];
    const float* rw_W   = (const float*)d_in[4];
    const float* w1     = (const float*)d_in[5];
    const float* w2     = (const float*)d_in[6];
    const float* w2_b   = (const float*)d_in[7];
    const float* kw_W   = (const float*)d_in[8];
    const float* vw_W   = (const float*)d_in[9];
    const float* a1     = (const float*)d_in[10];
    const float* a2     = (const float*)d_in[11];
    const float* a2_b   = (const float*)d_in[12];
    const float* v1     = (const float*)d_in[13];
    const float* v2     = (const float*)d_in[14];
    const float* v2_b   = (const float*)d_in[15];
    const float* g1     = (const float*)d_in[16];
    const float* g2     = (const float*)d_in[17];
    const float* g2_b   = (const float*)d_in[18];
    const float* k_k    = (const float*)d_in[19];
    const float* k_a    = (const float*)d_in[20];
    const float* r_k    = (const float*)d_in[21];
    const float* gn_s   = (const float*)d_in[22];
    const float* gn_b   = (const float*)d_in[23];
    const float* out_W  = (const float*)d_in[24];

    float* out = (float*)d_out;
    float* y_out = out;
    float* state_out = out + (size_t)NT * DD;
    float* vf_out = state_out + (size_t)4 * NH * HSZ * HSZ;

    // ---- workspace carve (float units).
    float* p = (float*)d_ws;
    const size_t big = (size_t)NT * DD;   // 4,194,304
    const size_t half = big / 2;          // 2,097,152
    float* r_buf = p;   p += big;
    float* k_buf = p;   p += big;   // k0 -> k final in place
    float* v_buf = p;   p += big;   // v0 -> v final in place
    // x-region: 6 branch pairs (hi,lo), each pair = 'big' floats = 16 MB
    float* xreg = p;
    ushort* xrh = (ushort*)(xreg);            ushort* xrl = (ushort*)(xreg + half);
    ushort* xwh = (ushort*)(xreg + 2*half);   ushort* xwl = (ushort*)(xreg + 3*half);
    ushort* xkh = (ushort*)(xreg + 4*half);   ushort* xkl = (ushort*)(xreg + 5*half);
    ushort* xvh = (ushort*)(xreg + 6*half);   ushort* xvl = (ushort*)(xreg + 7*half);
    ushort* xah = (ushort*)(xreg + 8*half);   ushort* xal = (ushort*)(xreg + 9*half);
    ushort* xgh = (ushort*)(xreg + 10*half);  ushort* xgl = (ushort*)(xreg + 11*half);
    p += 12 * half;
    // overlays (valid after gemm_mega1 completes):
    float* w_buf   = xreg + 0 * half;   // wl -> wdec in place (16 MB over xr pair)
    float* a_buf   = xreg + 2 * half;   // over xw pair
    float* vg_buf  = xreg + 4 * half;   // over xk pair; reused as out_scan after E1
    float* os_buf  = vg_buf;
    float* g_buf   = xreg + 6 * half;   // over xv pair
    float* kkn_buf = xreg + 8 * half;   // over xa pair
    // Bt region: [3584][1024] bf16 hi + lo
    float* btreg = p;
    ushort* Bth = (ushort*)btreg;                      // 1,835,008 floats
    ushort* Btl = (ushort*)(btreg + 1835008);
    p += 2 * 1835008;
    // overlays on Bt region (valid after gemm_mega1):
    ushort* z_bf  = (ushort*)btreg;                    // 2,097,152 floats
    ushort* outTh = (ushort*)(btreg + 2097152);        // 524,288 floats
    // stage-2 transposed weights (hi/lo)
    ushort* w2Th = (ushort*)p; p += 32768; ushort* w2Tl = (ushort*)p; p += 32768;
    ushort* a2Th = (ushort*)p; p += 32768; ushort* a2Tl = (ushort*)p; p += 32768;
    ushort* v2Th = (ushort*)p; p += 16384; ushort* v2Tl = (ushort*)p; p += 16384;
    ushort* g2Th = (ushort*)p; p += 65536; ushort* g2Tl = (ushort*)p; p += 65536;
    // LoRA hidden buffers (hi/lo)
    ushort* hwh = (ushort*)p; p += 131072; ushort* hwl = (ushort*)p; p += 131072;
    ushort* hah = (ushort*)p; p += 131072; ushort* hal = (ushort*)p; p += 131072;
    ushort* hvh = (ushort*)p; p += 65536;  ushort* hvl = (ushort*)p; p += 65536;
    ushort* hgh = (ushort*)p; p += 262144; ushort* hgl = (ushort*)p; p += 262144;
    float* rks_buf = p;        p += 65536;

    dim3 blk(256);
    dim3 t32x8(32, 8);

    // ---- ALL stage-1/stage-2 transposes in ONE dispatch (11 jobs, 3872 tiles)
    TJobs jobs;
    jobs.j[0]  = { rw_W, Bth + (size_t)0 * 1024,    Btl + (size_t)0 * 1024,    1024, 1024, 32, 1024 };
    jobs.j[1]  = { kw_W, Bth + (size_t)1024 * 1024, Btl + (size_t)1024 * 1024, 1024, 1024, 32, 1024 };
    jobs.j[2]  = { vw_W, Bth + (size_t)2048 * 1024, Btl + (size_t)2048 * 1024, 1024, 1024, 32, 1024 };
    jobs.j[3]  = { w1,   Bth + (size_t)3072 * 1024, Btl + (size_t)3072 * 1024, 1024, 64,   4,  128 };
    jobs.j[4]  = { a1,   Bth + (size_t)3200 * 1024, Btl + (size_t)3200 * 1024, 1024, 64,   4,  128 };
    jobs.j[5]  = { v1,   Bth + (size_t)3328 * 1024, Btl + (size_t)3328 * 1024, 1024, 32,   4,  128 };
    jobs.j[6]  = { g1,   Bth + (size_t)3456 * 1024, Btl + (size_t)3456 * 1024, 1024, 128,  4,  128 };
    jobs.j[7]  = { w2,   w2Th, w2Tl, 64,  1024, 32, 64 };
    jobs.j[8]  = { a2,   a2Th, a2Tl, 64,  1024, 32, 64 };
    jobs.j[9]  = { v2,   v2Th, v2Tl, 32,  1024, 32, 32 };
    jobs.j[10] = { g2,   g2Th, g2Tl, 128, 1024, 32, 128 };
    transpose_all<<<dim3(3872), t32x8, 0, stream>>>(jobs);

    // ---- fused token-shift mixes (hi/lo) for all 6 branches
    mix6<<<NT, blk, 0, stream>>>(cur, prev, rwkvag,
                                 xrh, xrl, xwh, xwl, xkh, xkl,
                                 xvh, xvl, xah, xal, xgh, xgl);

    // ---- MEGA stage-1 GEMM (r,k,v + 4 LoRA stage-1), 128^2, counted-vmcnt dbuf
    gemm_mega1<<<dim3(32, 28), blk, 0, stream>>>(
        xrh, xrl, xwh, xwl, xkh, xkl, xvh, xvl, xah, xal, xgh, xgl,
        Bth, Btl, r_buf, k_buf, v_buf,
        hwh, hwl, hah, hal, hvh, hvl, hgh, hgl);

    // out_W transpose (Bt region is free from here on; outTh overlays Btl)
    transpose_pad<<<dim3(32, 32), t32x8, 0, stream>>>(out_W, outTh, nullptr, 1024, 1024);

    // ---- MEGA stage-2 GEMM (w2/a2/v2/g2), overwrites x-region overlays
    gemm_mega2<<<dim3(32, 32), blk, 0, stream>>>(
        hwh, hwl, hah, hal, hvh, hvl, hgh, hgl,
        w2Th, w2Tl, a2Th, a2Tl, v2Th, v2Tl, g2Th, g2Tl,
        w2_b, a2_b, v2_b, g2_b,
        w_buf, a_buf, vg_buf, g_buf);

    // ---- elementwise + scan + epilogue
    elemwise1<<<NT, blk, 0, stream>>>(r_buf, w_buf, k_buf, v_buf, kkn_buf, a_buf,
                                      vg_buf, vfirst, k_k, k_a, r_k, rks_buf);

    scan_kernel<<<dim3(64, 4), blk, 0, stream>>>(r_buf, w_buf, k_buf, kkn_buf, a_buf, v_buf,
                                                 os_buf, state_out);

    elemwise2<<<NT, blk, 0, stream>>>(os_buf, rks_buf, v_buf, g_buf, gn_s, gn_b, z_bf);

    // ---- y = z @ out_W (plain bf16, dbuf)
    gemm_bf16s<<<dim3(32, 8), blk, 0, stream>>>(z_bf, outTh, y_out, 1024, 1024);

    // ---- v_first passthrough
    hipMemcpyAsync(vf_out, vfirst, (size_t)NT * DD * sizeof(float),
                   hipMemcpyDeviceToDevice, stream);
}

// Round 12
// 493.188 us; speedup vs baseline: 1.1265x; 1.0170x over previous
//
#include <hip/hip_runtime.h>
#include <math.h>

#define NT 4096      // B*T
#define DD 1024      // D == DM
#define NH 16
#define HSZ 64
#define GN_EPS 1e-5f
#define DECAY_C -0.606531f

typedef __attribute__((ext_vector_type(8))) short short8;
typedef __attribute__((ext_vector_type(4))) float float4v;

#define GLB(p) ((const __attribute__((address_space(1))) void*)(p))
#define LDS(p) ((__attribute__((address_space(3))) void*)(p))

#define MEMFENCE asm volatile("" ::: "memory")

__device__ __forceinline__ float sigm(float x) { return 1.f / (1.f + __expf(-x)); }

__device__ __forceinline__ unsigned short f2bf(float f) {
    unsigned int u = __float_as_uint(f);
    u = (u + 0x7fffu + ((u >> 16) & 1u)) >> 16;
    return (unsigned short)u;
}
__device__ __forceinline__ float bf2f(unsigned short h) {
    return __uint_as_float(((unsigned int)h) << 16);
}

// Full sum across each 16-lane row via DPP row_ror rotate-adds (VALU pipe only)
__device__ __forceinline__ float row_sum16(float x) {
    int t;
    t = __builtin_amdgcn_update_dpp(0, __float_as_int(x), 0x128, 0xF, 0xF, true); // ror 8
    x += __int_as_float(t);
    t = __builtin_amdgcn_update_dpp(0, __float_as_int(x), 0x124, 0xF, 0xF, true); // ror 4
    x += __int_as_float(t);
    t = __builtin_amdgcn_update_dpp(0, __float_as_int(x), 0x122, 0xF, 0xF, true); // ror 2
    x += __int_as_float(t);
    t = __builtin_amdgcn_update_dpp(0, __float_as_int(x), 0x121, 0xF, 0xF, true); // ror 1
    x += __int_as_float(t);
    return x;
}

// ---------------- transpose + split-cast with zero-padding (single job):
// W[K][N] fp32 -> Wt[Npad][K] hi/lo bf16. grid.x covers Npad/32; cols >= N -> 0.
__global__ __launch_bounds__(256)
void transpose_pad(const float* __restrict__ W, ushort* __restrict__ Wh,
                   ushort* __restrict__ Wl, int K, int N)
{
    __shared__ float tile[32][33];
    const int bx = blockIdx.x * 32;  // N (padded)
    const int by = blockIdx.y * 32;  // K
    const int tx = threadIdx.x, ty = threadIdx.y;  // 32 x 8
#pragma unroll
    for (int i = 0; i < 32; i += 8) {
        float v = 0.f;
        if (bx + tx < N) v = W[(size_t)(by + ty + i) * N + bx + tx];
        tile[ty + i][tx] = v;
    }
    __syncthreads();
#pragma unroll
    for (int i = 0; i < 32; i += 8) {
        float v = tile[tx][ty + i];
        ushort h = f2bf(v);
        size_t o = (size_t)(bx + ty + i) * K + by + tx;
        Wh[o] = h;
        if (Wl) Wl[o] = f2bf(v - bf2f(h));
    }
}

// ---------------- combined prep: mix6 (blocks 0..NT-1) + 11 transpose jobs
// (blocks NT..NT+3871) in ONE dispatch. Flat 256 threads; transpose path
// derives (tx,ty) = (tid&31, tid>>5). Bodies identical to verified kernels.
struct TJob { const float* W; ushort* Wh; ushort* Wl; int K, N, nx, cnt; };
struct TJobs { TJob j[11]; };

__global__ __launch_bounds__(256)
void prep_all(const float* __restrict__ cur, const float* __restrict__ prev,
              const float* __restrict__ lam,
              ushort* __restrict__ xrh, ushort* __restrict__ xrl,
              ushort* __restrict__ xwh, ushort* __restrict__ xwl,
              ushort* __restrict__ xkh, ushort* __restrict__ xkl,
              ushort* __restrict__ xvh, ushort* __restrict__ xvl,
              ushort* __restrict__ xah, ushort* __restrict__ xal,
              ushort* __restrict__ xgh, ushort* __restrict__ xgl,
              TJobs jobs)
{
    __shared__ float tile[32][33];
    if (blockIdx.x < NT) {
        // ---- mix6 body (verified)
        const int tok = blockIdx.x;
        const int d0 = threadIdx.x * 4;
        const size_t base = (size_t)tok * DD + d0;
        float4 c = *(const float4*)(cur + base);
        float4 p = *(const float4*)(prev + base);
        float dx = p.x - c.x, dy = p.y - c.y, dz = p.z - c.z, dw = p.w - c.w;
        ushort* hs[6] = {xrh, xwh, xkh, xvh, xah, xgh};
        ushort* ls[6] = {xrl, xwl, xkl, xvl, xal, xgl};
#pragma unroll
        for (int j = 0; j < 6; j++) {
            float4 l = *(const float4*)(lam + j * DD + d0);
            float m0 = c.x + l.x * dx;
            float m1 = c.y + l.y * dy;
            float m2 = c.z + l.z * dz;
            float m3 = c.w + l.w * dw;
            ushort4 h;
            h.x = f2bf(m0); h.y = f2bf(m1); h.z = f2bf(m2); h.w = f2bf(m3);
            *(ushort4*)(hs[j] + base) = h;
            ushort4 lo;
            lo.x = f2bf(m0 - bf2f(h.x));
            lo.y = f2bf(m1 - bf2f(h.y));
            lo.z = f2bf(m2 - bf2f(h.z));
            lo.w = f2bf(m3 - bf2f(h.w));
            *(ushort4*)(ls[j] + base) = lo;
        }
        return;
    }
    // ---- transpose path (verified transpose_all body)
    int rem = blockIdx.x - NT;
    int ji = 0;
    while (ji < 10 && rem >= jobs.j[ji].cnt) { rem -= jobs.j[ji].cnt; ji++; }
    const float* W = jobs.j[ji].W;
    ushort* Wh = jobs.j[ji].Wh;
    ushort* Wl = jobs.j[ji].Wl;
    const int K = jobs.j[ji].K, N = jobs.j[ji].N, nx = jobs.j[ji].nx;
    const int bx = (rem % nx) * 32;
    const int by = (rem / nx) * 32;
    const int tx = threadIdx.x & 31, ty = threadIdx.x >> 5;  // 32 x 8
#pragma unroll
    for (int i = 0; i < 32; i += 8) {
        float v = 0.f;
        if (bx + tx < N) v = W[(size_t)(by + ty + i) * N + bx + tx];
        tile[ty + i][tx] = v;
    }
    __syncthreads();
#pragma unroll
    for (int i = 0; i < 32; i += 8) {
        float v = tile[tx][ty + i];
        ushort h = f2bf(v);
        size_t o = (size_t)(bx + ty + i) * K + by + tx;
        Wh[o] = h;
        Wl[o] = f2bf(v - bf2f(h));
    }
}

// LDS chunk swizzle: row-dependent XOR on the 16B-chunk index.
// bank-group g = (row*4 + chunk) % 8; chunk = quad ^ ((row>>1)&3) spreads each
// 16-lane quarter-wave over all 8 groups (2 lanes each -> free).
#define SWZ(r) (((r) >> 1) & 3)

// ---------------- MEGA stage-1 GEMM: 128x128 tiles, double-buffered with
// COUNTED vmcnt + raw barriers (T4): no vmcnt(0) drain in the main loop.
// N = 3584 = r[0,1024) k[1024,2048) v[2048,3072) w1@3072(64) a1@3200(64)
//            v1@3328(32) g1@3456(128). K=1024, bf16x3 split, per-colblock A.
__global__ __launch_bounds__(256)
void gemm_mega1(const ushort* __restrict__ xrh, const ushort* __restrict__ xrl,
                const ushort* __restrict__ xwh, const ushort* __restrict__ xwl,
                const ushort* __restrict__ xkh, const ushort* __restrict__ xkl,
                const ushort* __restrict__ xvh, const ushort* __restrict__ xvl,
                const ushort* __restrict__ xah, const ushort* __restrict__ xal,
                const ushort* __restrict__ xgh, const ushort* __restrict__ xgl,
                const ushort* __restrict__ Bth, const ushort* __restrict__ Btl,
                float* __restrict__ r_buf, float* __restrict__ k_buf,
                float* __restrict__ v_buf,
                ushort* __restrict__ hwh, ushort* __restrict__ hwl,
                ushort* __restrict__ hah, ushort* __restrict__ hal,
                ushort* __restrict__ hvh, ushort* __restrict__ hvl,
                ushort* __restrict__ hgh, ushort* __restrict__ hgl)
{
    __shared__ ushort As[2][2][128 * 32];   // [dbuf][hi/lo]  32 KB
    __shared__ ushort Bs[2][2][128 * 32];   // 32 KB
    const int cb = blockIdx.y;
    const ushort* Ah; const ushort* Al;
    if (cb < 8)       { Ah = xrh; Al = xrl; }
    else if (cb < 16) { Ah = xkh; Al = xkl; }
    else if (cb < 24) { Ah = xvh; Al = xvl; }
    else if (cb == 24){ Ah = xwh; Al = xwl; }
    else if (cb == 25){ Ah = xah; Al = xal; }
    else if (cb == 26){ Ah = xvh; Al = xvl; }
    else              { Ah = xgh; Al = xgl; }

    const int tid = threadIdx.x;
    const int rowBase = blockIdx.x * 128;
    const int colBase = cb * 128;
    const int lane = tid & 63;
    const int wave = tid >> 6;
    const int wm = wave >> 1, wn = wave & 1;
    const int m15 = lane & 15, quad = lane >> 4;

    float4v zero4 = {0.f, 0.f, 0.f, 0.f};
    float4v acc[4][4];
#pragma unroll
    for (int i = 0; i < 4; i++)
#pragma unroll
        for (int j = 0; j < 4; j++) acc[i][j] = zero4;

#define STAGE1(kk, bb) do {                                                       \
    const int k0_ = (kk) * 32;                                                    \
    _Pragma("unroll")                                                             \
    for (int i_ = 0; i_ < 2; i_++) {                                              \
        int idx_ = i_ * 256 + tid;                                                \
        int r_ = idx_ >> 2, seg_ = idx_ & 3;                                      \
        int sg_ = seg_ ^ SWZ(r_);   /* pre-swizzled source; LDS dest linear */    \
        size_t aoff_ = (size_t)(rowBase + r_) * 1024 + k0_ + sg_ * 8;             \
        size_t boff_ = (size_t)(colBase + r_) * 1024 + k0_ + sg_ * 8;             \
        int dst_ = (i_ * 256 + (tid & ~63)) * 8;                                  \
        __builtin_amdgcn_global_load_lds(GLB(Ah + aoff_),  LDS(&As[bb][0][0] + dst_), 16, 0, 0); \
        __builtin_amdgcn_global_load_lds(GLB(Al + aoff_),  LDS(&As[bb][1][0] + dst_), 16, 0, 0); \
        __builtin_amdgcn_global_load_lds(GLB(Bth + boff_), LDS(&Bs[bb][0][0] + dst_), 16, 0, 0); \
        __builtin_amdgcn_global_load_lds(GLB(Btl + boff_), LDS(&Bs[bb][1][0] + dst_), 16, 0, 0); \
    }                                                                             \
} while (0)

    STAGE1(0, 0);                       // 8 loads -> buf0
    STAGE1(1, 1);                       // 8 loads -> buf1 (16 outstanding)
    asm volatile("s_waitcnt vmcnt(8)" ::: "memory");   // buf0 landed
    __builtin_amdgcn_s_barrier();
    MEMFENCE;

    for (int kt = 0; kt < 32; kt++) {
        const int buf = kt & 1;

        short8 ah[4], bh[4], al[4], bl[4];
#pragma unroll
        for (int mi = 0; mi < 4; mi++) {
            int ra = wm * 64 + mi * 16 + m15;
            int cs = (quad ^ SWZ(ra)) * 8;
            ah[mi] = *(const short8*)(&As[buf][0][0] + ra * 32 + cs);
            al[mi] = *(const short8*)(&As[buf][1][0] + ra * 32 + cs);
        }
#pragma unroll
        for (int ni = 0; ni < 4; ni++) {
            int rb = wn * 64 + ni * 16 + m15;
            int cs = (quad ^ SWZ(rb)) * 8;
            bh[ni] = *(const short8*)(&Bs[buf][0][0] + rb * 32 + cs);
            bl[ni] = *(const short8*)(&Bs[buf][1][0] + rb * 32 + cs);
        }
#pragma unroll
        for (int mi = 0; mi < 4; mi++)
#pragma unroll
            for (int ni = 0; ni < 4; ni++) {
                acc[mi][ni] = __builtin_amdgcn_mfma_f32_16x16x32_bf16(al[mi], bh[ni], acc[mi][ni], 0, 0, 0);
                acc[mi][ni] = __builtin_amdgcn_mfma_f32_16x16x32_bf16(ah[mi], bl[ni], acc[mi][ni], 0, 0, 0);
                acc[mi][ni] = __builtin_amdgcn_mfma_f32_16x16x32_bf16(ah[mi], bh[ni], acc[mi][ni], 0, 0, 0);
            }

        if (kt == 31) break;

        MEMFENCE;
        __builtin_amdgcn_s_barrier();   // all waves done reading buf[kt]
        MEMFENCE;
        if (kt < 30) {
            STAGE1(kt + 2, buf);        // refill the buffer just read
            asm volatile("s_waitcnt vmcnt(8)" ::: "memory");  // stage(kt+1) landed
        } else {
            asm volatile("s_waitcnt vmcnt(0)" ::: "memory");  // stage(31) landed
        }
        __builtin_amdgcn_s_barrier();   // buf[kt+1] ready for everyone
        MEMFENCE;
    }
#undef STAGE1

#pragma unroll
    for (int mi = 0; mi < 4; mi++) {
#pragma unroll
        for (int ni = 0; ni < 4; ni++) {
            int c = wn * 64 + ni * 16 + m15;   // col within 128-tile
#pragma unroll
            for (int rr = 0; rr < 4; rr++) {
                int row = rowBase + wm * 64 + mi * 16 + quad * 4 + rr;
                float v = acc[mi][ni][rr];
                if (cb < 24) {
                    float* dst = (cb < 8) ? r_buf : (cb < 16) ? k_buf : v_buf;
                    int n = (cb & 7) * 128 + c;
                    dst[(size_t)row * 1024 + n] = v;
                } else if (cb == 24) {
                    if (c < 64) {
                        float t = tanhf(v);
                        ushort h = f2bf(t);
                        hwh[(size_t)row * 64 + c] = h;
                        hwl[(size_t)row * 64 + c] = f2bf(t - bf2f(h));
                    }
                } else if (cb == 25) {
                    if (c < 64) {
                        ushort h = f2bf(v);
                        hah[(size_t)row * 64 + c] = h;
                        hal[(size_t)row * 64 + c] = f2bf(v - bf2f(h));
                    }
                } else if (cb == 26) {
                    if (c < 32) {
                        ushort h = f2bf(v);
                        hvh[(size_t)row * 32 + c] = h;
                        hvl[(size_t)row * 32 + c] = f2bf(v - bf2f(h));
                    }
                } else {
                    float t = sigm(v);
                    ushort h = f2bf(t);
                    hgh[(size_t)row * 128 + c] = h;
                    hgl[(size_t)row * 128 + c] = f2bf(t - bf2f(h));
                }
            }
        }
    }
}

// ---------------- MEGA stage-2 GEMM: 4 LoRA stage-2 products in one dispatch.
// blockIdx.y: 0-7 w2(K=64,none), 8-15 a2(K=64,sigm), 16-23 v2(K=32,sigm),
// 24-31 g2(K=128,none). All outputs fp32 [4096][1024].
__global__ __launch_bounds__(256)
void gemm_mega2(const ushort* __restrict__ hwh, const ushort* __restrict__ hwl,
                const ushort* __restrict__ hah, const ushort* __restrict__ hal,
                const ushort* __restrict__ hvh, const ushort* __restrict__ hvl,
                const ushort* __restrict__ hgh, const ushort* __restrict__ hgl,
                const ushort* __restrict__ w2Th, const ushort* __restrict__ w2Tl,
                const ushort* __restrict__ a2Th, const ushort* __restrict__ a2Tl,
                const ushort* __restrict__ v2Th, const ushort* __restrict__ v2Tl,
                const ushort* __restrict__ g2Th, const ushort* __restrict__ g2Tl,
                const float* __restrict__ w2_b, const float* __restrict__ a2_b,
                const float* __restrict__ v2_b, const float* __restrict__ g2_b,
                float* __restrict__ w_buf, float* __restrict__ a_buf,
                float* __restrict__ vg_buf, float* __restrict__ g_buf)
{
    __shared__ ushort AsH[128 * 32];
    __shared__ ushort BsH[128 * 32];
    __shared__ ushort AsL[128 * 32];
    __shared__ ushort BsL[128 * 32];
    const int cb = blockIdx.y;
    const int seg = cb >> 3;
    const int K = (seg == 2) ? 32 : (seg == 3) ? 128 : 64;
    const ushort *Ah, *Al, *Bh, *Bl;
    const float* bias;
    float* outp;
    if (seg == 0) { Ah = hwh; Al = hwl; Bh = w2Th; Bl = w2Tl; bias = w2_b; outp = w_buf; }
    else if (seg == 1) { Ah = hah; Al = hal; Bh = a2Th; Bl = a2Tl; bias = a2_b; outp = a_buf; }
    else if (seg == 2) { Ah = hvh; Al = hvl; Bh = v2Th; Bl = v2Tl; bias = v2_b; outp = vg_buf; }
    else { Ah = hgh; Al = hgl; Bh = g2Th; Bl = g2Tl; bias = g2_b; outp = g_buf; }

    const int tid = threadIdx.x;
    const int rowBase = blockIdx.x * 128;
    const int colBase = (cb & 7) * 128;
    const int lane = tid & 63;
    const int wave = tid >> 6;
    const int wm = wave >> 1, wn = wave & 1;
    const int m15 = lane & 15, quad = lane >> 4;

    float4v zero4 = {0.f, 0.f, 0.f, 0.f};
    float4v acc[4][4];
#pragma unroll
    for (int i = 0; i < 4; i++)
#pragma unroll
        for (int j = 0; j < 4; j++) acc[i][j] = zero4;

    for (int k0 = 0; k0 < K; k0 += 32) {
#pragma unroll
        for (int i = 0; i < 2; i++) {
            int idx = i * 256 + tid;
            int r = idx >> 2, s8 = idx & 3;
            int sg = s8 ^ SWZ(r);   // pre-swizzled source, linear LDS dest
            size_t aoff = (size_t)(rowBase + r) * K + k0 + sg * 8;
            size_t boff = (size_t)(colBase + r) * K + k0 + sg * 8;
            int dst = (i * 256 + (tid & ~63)) * 8;
            __builtin_amdgcn_global_load_lds(GLB(Ah + aoff), LDS(AsH + dst), 16, 0, 0);
            __builtin_amdgcn_global_load_lds(GLB(Bh + boff), LDS(BsH + dst), 16, 0, 0);
            __builtin_amdgcn_global_load_lds(GLB(Al + aoff), LDS(AsL + dst), 16, 0, 0);
            __builtin_amdgcn_global_load_lds(GLB(Bl + boff), LDS(BsL + dst), 16, 0, 0);
        }
        __syncthreads();
        short8 ah[4], bh[4], al[4], bl[4];
#pragma unroll
        for (int mi = 0; mi < 4; mi++) {
            int ra = wm * 64 + mi * 16 + m15;
            int cs = (quad ^ SWZ(ra)) * 8;
            ah[mi] = *(const short8*)(AsH + ra * 32 + cs);
            al[mi] = *(const short8*)(AsL + ra * 32 + cs);
        }
#pragma unroll
        for (int ni = 0; ni < 4; ni++) {
            int rb = wn * 64 + ni * 16 + m15;
            int cs = (quad ^ SWZ(rb)) * 8;
            bh[ni] = *(const short8*)(BsH + rb * 32 + cs);
            bl[ni] = *(const short8*)(BsL + rb * 32 + cs);
        }
#pragma unroll
        for (int mi = 0; mi < 4; mi++)
#pragma unroll
            for (int ni = 0; ni < 4; ni++) {
                acc[mi][ni] = __builtin_amdgcn_mfma_f32_16x16x32_bf16(al[mi], bh[ni], acc[mi][ni], 0, 0, 0);
                acc[mi][ni] = __builtin_amdgcn_mfma_f32_16x16x32_bf16(ah[mi], bl[ni], acc[mi][ni], 0, 0, 0);
                acc[mi][ni] = __builtin_amdgcn_mfma_f32_16x16x32_bf16(ah[mi], bh[ni], acc[mi][ni], 0, 0, 0);
            }
        __syncthreads();
    }

#pragma unroll
    for (int mi = 0; mi < 4; mi++) {
#pragma unroll
        for (int ni = 0; ni < 4; ni++) {
            int col = colBase + wn * 64 + ni * 16 + m15;
            float bv = bias[col];
#pragma unroll
            for (int rr = 0; rr < 4; rr++) {
                int row = rowBase + wm * 64 + mi * 16 + quad * 4 + rr;
                float v = acc[mi][ni][rr] + bv;
                if (seg == 1 || seg == 2) v = sigm(v);
                outp[(size_t)row * 1024 + col] = v;
            }
        }
    }
}

// ---------------- plain bf16 GEMM (final out-projection), counted-vmcnt dbuf
// (exact port of the round-8 verified version).
__global__ __launch_bounds__(256)
void gemm_bf16s(const ushort* __restrict__ Ah, const ushort* __restrict__ Bh,
                float* __restrict__ outF, int N, int K)
{
    __shared__ ushort As2[2][128 * 32];
    __shared__ ushort Bs2[2][128 * 32];
    const int tid = threadIdx.x;
    const int rowBase = blockIdx.x * 128;
    const int colBase = blockIdx.y * 128;
    const int lane = tid & 63;
    const int wave = tid >> 6;
    const int wm = wave >> 1, wn = wave & 1;
    const int m15 = lane & 15, quad = lane >> 4;

    float4v zero4 = {0.f, 0.f, 0.f, 0.f};
    float4v acc[4][4];
#pragma unroll
    for (int i = 0; i < 4; i++)
#pragma unroll
        for (int j = 0; j < 4; j++) acc[i][j] = zero4;

#define STAGE3(kk, bb) do {                                                       \
    const int k0_ = (kk) * 32;                                                    \
    _Pragma("unroll")                                                             \
    for (int i_ = 0; i_ < 2; i_++) {                                              \
        int idx_ = i_ * 256 + tid;                                                \
        int r_ = idx_ >> 2, seg_ = idx_ & 3;                                      \
        int sg_ = seg_ ^ SWZ(r_);                                                 \
        size_t aoff_ = (size_t)(rowBase + r_) * K + k0_ + sg_ * 8;                \
        size_t boff_ = (size_t)(colBase + r_) * K + k0_ + sg_ * 8;                \
        int dst_ = (i_ * 256 + (tid & ~63)) * 8;                                  \
        __builtin_amdgcn_global_load_lds(GLB(Ah + aoff_), LDS(&As2[bb][0] + dst_), 16, 0, 0); \
        __builtin_amdgcn_global_load_lds(GLB(Bh + boff_), LDS(&Bs2[bb][0] + dst_), 16, 0, 0); \
    }                                                                             \
} while (0)

    const int nk = K >> 5;          // 32 for K=1024
    STAGE3(0, 0);                   // 4 loads -> buf0
    STAGE3(1, 1);                   // 4 loads -> buf1 (8 outstanding)
    asm volatile("s_waitcnt vmcnt(4)" ::: "memory");   // buf0 landed
    __builtin_amdgcn_s_barrier();
    MEMFENCE;

    for (int kt = 0; kt < nk; kt++) {
        const int buf = kt & 1;
        short8 ah[4], bh[4];
#pragma unroll
        for (int mi = 0; mi < 4; mi++) {
            int ra = wm * 64 + mi * 16 + m15;
            ah[mi] = *(const short8*)(&As2[buf][0] + ra * 32 + (quad ^ SWZ(ra)) * 8);
        }
#pragma unroll
        for (int ni = 0; ni < 4; ni++) {
            int rb = wn * 64 + ni * 16 + m15;
            bh[ni] = *(const short8*)(&Bs2[buf][0] + rb * 32 + (quad ^ SWZ(rb)) * 8);
        }
#pragma unroll
        for (int mi = 0; mi < 4; mi++)
#pragma unroll
            for (int ni = 0; ni < 4; ni++)
                acc[mi][ni] = __builtin_amdgcn_mfma_f32_16x16x32_bf16(ah[mi], bh[ni], acc[mi][ni], 0, 0, 0);

        if (kt == nk - 1) break;

        MEMFENCE;
        __builtin_amdgcn_s_barrier();   // all waves done reading buf[kt]
        MEMFENCE;
        if (kt < nk - 2) {
            STAGE3(kt + 2, buf);        // refill just-read buffer (4 loads)
            asm volatile("s_waitcnt vmcnt(4)" ::: "memory");  // stage(kt+1) landed
        } else {
            asm volatile("s_waitcnt vmcnt(0)" ::: "memory");
        }
        __builtin_amdgcn_s_barrier();   // buf[kt+1] ready
        MEMFENCE;
    }
#undef STAGE3

#pragma unroll
    for (int mi = 0; mi < 4; mi++) {
#pragma unroll
        for (int ni = 0; ni < 4; ni++) {
            int col = colBase + wn * 64 + ni * 16 + m15;
#pragma unroll
            for (int rr = 0; rr < 4; rr++) {
                int row = rowBase + wm * 64 + mi * 16 + quad * 4 + rr;
                outF[(size_t)row * N + col] = acc[mi][ni][rr];
            }
        }
    }
}

// ---------------- elementwise stage 1 (fp32)
__global__ __launch_bounds__(256)
void elemwise1(const float* __restrict__ r_buf, float* __restrict__ wl_buf,
               float* __restrict__ k_buf, float* __restrict__ v_buf,
               float* __restrict__ kkn_buf, const float* __restrict__ a_buf,
               const float* __restrict__ vg_buf, const float* __restrict__ vfirst,
               const float* __restrict__ kkw, const float* __restrict__ kaw,
               const float* __restrict__ rkw, float* __restrict__ rk_sum)
{
    const int tok = blockIdx.x;
    const int tid = threadIdx.x;
    const int d0 = tid * 4;
    const size_t base = (size_t)tok * DD + d0;

    float4 k0 = *(const float4*)(k_buf + base);
    float4 a4 = *(const float4*)(a_buf + base);
    float4 wl = *(const float4*)(wl_buf + base);
    float4 v0 = *(const float4*)(v_buf + base);
    float4 vg = *(const float4*)(vg_buf + base);
    float4 vf = *(const float4*)(vfirst + base);
    float4 r4 = *(const float4*)(r_buf + base);
    float4 kkc = *(const float4*)(kkw + d0);
    float4 kac = *(const float4*)(kaw + d0);
    float4 rkc = *(const float4*)(rkw + d0);

    float kk0 = k0.x * kkc.x, kk1 = k0.y * kkc.y, kk2 = k0.z * kkc.z, kk3 = k0.w * kkc.w;
    float ss = kk0 * kk0 + kk1 * kk1 + kk2 * kk2 + kk3 * kk3;
    ss += __shfl_xor(ss, 1); ss += __shfl_xor(ss, 2);
    ss += __shfl_xor(ss, 4); ss += __shfl_xor(ss, 8);
    float rn = rsqrtf(ss);
    float4 kkn = { kk0 * rn, kk1 * rn, kk2 * rn, kk3 * rn };
    *(float4*)(kkn_buf + base) = kkn;

    float4 kf;
    kf.x = k0.x * (1.f + (a4.x - 1.f) * kac.x);
    kf.y = k0.y * (1.f + (a4.y - 1.f) * kac.y);
    kf.z = k0.z * (1.f + (a4.z - 1.f) * kac.z);
    kf.w = k0.w * (1.f + (a4.w - 1.f) * kac.w);
    *(float4*)(k_buf + base) = kf;

    float rk = r4.x * kf.x * rkc.x + r4.y * kf.y * rkc.y + r4.z * kf.z * rkc.z + r4.w * kf.w * rkc.w;
    rk += __shfl_xor(rk, 1); rk += __shfl_xor(rk, 2);
    rk += __shfl_xor(rk, 4); rk += __shfl_xor(rk, 8);
    if ((tid & 15) == 0) rk_sum[(size_t)tok * NH + (tid >> 4)] = rk;

    float4 vfin;
    vfin.x = v0.x + (vf.x - v0.x) * vg.x;
    vfin.y = v0.y + (vf.y - v0.y) * vg.y;
    vfin.z = v0.z + (vf.z - v0.z) * vg.z;
    vfin.w = v0.w + (vf.w - v0.w) * vg.w;
    *(float4*)(v_buf + base) = vfin;

    float4 wd;
    wd.x = __expf(DECAY_C * sigm(wl.x));
    wd.y = __expf(DECAY_C * sigm(wl.y));
    wd.z = __expf(DECAY_C * sigm(wl.z));
    wd.w = __expf(DECAY_C * sigm(wl.w));
    *(float4*)(wl_buf + base) = wd;
}

// ---------------- sequential scan (best measured: v3 depth-4 + ypart pad 20,
// 128.0 us; ~128 us is this serial formulation's floor)
__global__ __launch_bounds__(256, 1)
void scan_kernel(const float* __restrict__ r_buf, const float* __restrict__ w_buf,
                 const float* __restrict__ k_buf, const float* __restrict__ kkn_buf,
                 const float* __restrict__ a_buf, const float* __restrict__ v_buf,
                 float* __restrict__ out_scan, float* __restrict__ state_out)
{
    __shared__ float vecJ[2][5][16][64];      // 40 KB
    __shared__ float vbuf2[2][16][16];        // 2 KB
    __shared__ float ypart[2][16][16][20];    // 40 KB  [buf][t][vrow][l16(pad 20)]
    const int bh = blockIdx.x;
    const int rg = blockIdx.y;
    const int b = bh >> 4, h = bh & 15;
    const int tid = threadIdx.x;
    const int row = tid >> 4, l16 = tid & 15;
    const int lofs = l16 * 4;
    const int rowbase = rg * 16;
    const size_t tok0 = ((size_t)b * 1024) * DD + h * HSZ;
    float s0 = 0.f, s1 = 0.f, s2 = 0.f, s3 = 0.f;

#define STAGE(cc, bb) do {                                                        \
    const int tt_ = tid >> 4;                                                     \
    const int dd4_ = (tid & 15) * 4;                                              \
    size_t gofs_ = tok0 + (size_t)((cc) * 16 + tt_) * DD + dd4_;                  \
    float* db_ = &vecJ[bb][0][0][0] + ((tid >> 6) << 8);                          \
    __builtin_amdgcn_global_load_lds(GLB(r_buf + gofs_),   LDS(db_),        16, 0, 0); \
    __builtin_amdgcn_global_load_lds(GLB(w_buf + gofs_),   LDS(db_ + 1024), 16, 0, 0); \
    __builtin_amdgcn_global_load_lds(GLB(k_buf + gofs_),   LDS(db_ + 2048), 16, 0, 0); \
    __builtin_amdgcn_global_load_lds(GLB(kkn_buf + gofs_), LDS(db_ + 3072), 16, 0, 0); \
    __builtin_amdgcn_global_load_lds(GLB(a_buf + gofs_),   LDS(db_ + 4096), 16, 0, 0); \
    if (tid < 64) {                                                               \
        size_t vofs_ = tok0 + (size_t)((cc) * 16 + (tid >> 2)) * DD + rowbase + (tid & 3) * 4; \
        __builtin_amdgcn_global_load_lds(GLB(v_buf + vofs_), LDS(&vbuf2[bb][0][0]), 16, 0, 0); \
    }                                                                             \
} while (0)

#define LD_TOK(P, tt) do {                                                        \
    P##r = *(const float4*)(vb + (tt) * 64 + lofs);                               \
    P##w = *(const float4*)(vb + 1024 + (tt) * 64 + lofs);                        \
    P##k = *(const float4*)(vb + 2048 + (tt) * 64 + lofs);                        \
    P##q = *(const float4*)(vb + 3072 + (tt) * 64 + lofs);                        \
    P##a = *(const float4*)(vb + 4096 + (tt) * 64 + lofs);                        \
    P##v = vbp[(tt) * 16 + row];                                                  \
} while (0)

#define STEP(P, tt) do {                                                          \
    float sa_ = P##q.x * s0;                                                      \
    sa_ = fmaf(P##q.y, s1, sa_);                                                  \
    sa_ = fmaf(P##q.z, s2, sa_);                                                  \
    sa_ = fmaf(P##q.w, s3, sa_);                                                  \
    sa_ = row_sum16(sa_);                                                         \
    float n0_ = P##q.x * P##a.x, n1_ = P##q.y * P##a.y;                           \
    float n2_ = P##q.z * P##a.z, n3_ = P##q.w * P##a.w;                           \
    float b0_ = fmaf(s0, P##w.x, P##v * P##k.x);                                  \
    float b1_ = fmaf(s1, P##w.y, P##v * P##k.y);                                  \
    float b2_ = fmaf(s2, P##w.z, P##v * P##k.z);                                  \
    float b3_ = fmaf(s3, P##w.w, P##v * P##k.w);                                  \
    s0 = fmaf(sa_, -n0_, b0_);                                                    \
    s1 = fmaf(sa_, -n1_, b1_);                                                    \
    s2 = fmaf(sa_, -n2_, b2_);                                                    \
    s3 = fmaf(sa_, -n3_, b3_);                                                    \
    float yp_ = P##r.x * s0;                                                      \
    yp_ = fmaf(P##r.y, s1, yp_);                                                  \
    yp_ = fmaf(P##r.z, s2, yp_);                                                  \
    yp_ = fmaf(P##r.w, s3, yp_);                                                  \
    ypart[buf][tt][row][l16] = yp_;                                               \
} while (0)

    STAGE(0, 0);
    __syncthreads();   // drains vmcnt -> chunk 0 resident

    for (int c = 0; c < 64; c++) {
        const int buf = c & 1;
        if (c < 63) STAGE(c + 1, buf ^ 1);   // in flight during the whole chunk
        const float* vb  = &vecJ[buf][0][0][0];
        const float* vbp = &vbuf2[buf][0][0];
        float4 Ar, Aw, Ak, Aq, Aa; float Av;
        float4 Br, Bw, Bk, Bq, Ba; float Bv;
        float4 Cr, Cw, Ck, Cq, Ca; float Cv;
        float4 Dr, Dw, Dk, Dq, Da; float Dv;
        LD_TOK(A, 0); LD_TOK(B, 1); LD_TOK(C, 2);
#pragma unroll
        for (int i4 = 0; i4 < 4; i4++) {
            LD_TOK(D, 4 * i4 + 3);
            STEP(A, 4 * i4);
            if (4 * i4 + 4 < 16) LD_TOK(A, 4 * i4 + 4);
            STEP(B, 4 * i4 + 1);
            if (4 * i4 + 5 < 16) LD_TOK(B, 4 * i4 + 5);
            STEP(C, 4 * i4 + 2);
            if (4 * i4 + 6 < 16) LD_TOK(C, 4 * i4 + 6);
            STEP(D, 4 * i4 + 3);
        }
        __syncthreads();  // ypart complete; also drains staged loads for c+1
        {
            const int t_ = tid >> 4, r_ = tid & 15;
            const float* yp = &ypart[buf][t_][r_][0];
            float4 y0 = *(const float4*)(yp);
            float4 y1 = *(const float4*)(yp + 4);
            float4 y2 = *(const float4*)(yp + 8);
            float4 y3 = *(const float4*)(yp + 12);
            float ys = ((y0.x + y0.y) + (y0.z + y0.w)) + ((y1.x + y1.y) + (y1.z + y1.w))
                     + ((y2.x + y2.y) + (y2.z + y2.w)) + ((y3.x + y3.y) + (y3.z + y3.w));
            out_scan[tok0 + (size_t)(c * 16 + t_) * DD + rowbase + r_] = ys;
        }
    }

#undef STAGE
#undef LD_TOK
#undef STEP

    float* so = state_out + ((size_t)(b * NH + h) * HSZ + rowbase + row) * HSZ + l16 * 4;
    float4 sv = {s0, s1, s2, s3};
    *(float4*)so = sv;
}

// ---------------- stage 2: GroupNorm + residual + gate -> z (plain bf16)
__global__ __launch_bounds__(256)
void elemwise2(const float* __restrict__ out_scan, const float* __restrict__ rk_sum,
               const float* __restrict__ v_buf, const float* __restrict__ g_buf,
               const float* __restrict__ gscale, const float* __restrict__ gbias,
               ushort* __restrict__ z_buf)
{
    const int tok = blockIdx.x;
    const int tid = threadIdx.x;
    const int d0 = tid * 4;
    const size_t base = (size_t)tok * DD + d0;

    float4 o = *(const float4*)(out_scan + base);
    float sm = o.x + o.y + o.z + o.w;
    float ss = o.x * o.x + o.y * o.y + o.z * o.z + o.w * o.w;
    sm += __shfl_xor(sm, 1); sm += __shfl_xor(sm, 2);
    sm += __shfl_xor(sm, 4); sm += __shfl_xor(sm, 8);
    ss += __shfl_xor(ss, 1); ss += __shfl_xor(ss, 2);
    ss += __shfl_xor(ss, 4); ss += __shfl_xor(ss, 8);
    float mu = sm * (1.f / 64.f);
    float var = ss * (1.f / 64.f) - mu * mu;
    float rs = rsqrtf(var + GN_EPS);
    float rk = rk_sum[(size_t)tok * NH + (tid >> 4)];

    float4 v4 = *(const float4*)(v_buf + base);
    float4 g4 = *(const float4*)(g_buf + base);
    float4 gs = *(const float4*)(gscale + d0);
    float4 gb = *(const float4*)(gbias + d0);
    ushort4 z;
    z.x = f2bf(((o.x - mu) * rs * gs.x + gb.x + rk * v4.x) * g4.x);
    z.y = f2bf(((o.y - mu) * rs * gs.y + gb.y + rk * v4.y) * g4.y);
    z.z = f2bf(((o.z - mu) * rs * gs.z + gb.z + rk * v4.z) * g4.z);
    z.w = f2bf(((o.w - mu) * rs * gs.w + gb.w + rk * v4.w) * g4.w);
    *(ushort4*)(z_buf + base) = z;
}

extern "C" void kernel_launch(void* const* d_in, const int* in_sizes, int n_in,
                              void* d_out, int out_size, void* d_ws, size_t ws_size,
                              hipStream_t stream) {
    const float* cur    = (const float*)d_in[0];
    const float* prev   = (const float*)d_in[1];
    const float* vfirst = (const float*)d_in[2];
    const float* rwkvag = (const float*)d_in[3];
    const float* rw_W   = (const float*)d_in[4];
    const float* w1     = (const float*)d_in[5];
    const float* w2     = (const float*)d_in[6];
    const float* w2_b   = (const float*)d_in[7];
    const float* kw_W   = (const float*)d_in[8];
    const float* vw_W   = (const float*)d_in[9];
    const float* a1     = (const float*)d_in[10];
    const float* a2     = (const float*)d_in[11];
    const float* a2_b   = (const float*)d_in[12];
    const float* v1     = (const float*)d_in[13];
    const float* v2     = (const float*)d_in[14];
    const float* v2_b   = (const float*)d_in[15];
    const float* g1     = (const float*)d_in[16];
    const float* g2     = (const float*)d_in[17];
    const float* g2_b   = (const float*)d_in[18];
    const float* k_k    = (const float*)d_in[19];
    const float* k_a    = (const float*)d_in[20];
    const float* r_k    = (const float*)d_in[21];
    const float* gn_s   = (const float*)d_in[22];
    const float* gn_b   = (const float*)d_in[23];
    const float* out_W  = (const float*)d_in[24];

    float* out = (float*)d_out;
    float* y_out = out;
    float* state_out = out + (size_t)NT * DD;
    float* vf_out = state_out + (size_t)4 * NH * HSZ * HSZ;

    // ---- workspace carve (float units).
    float* p = (float*)d_ws;
    const size_t big = (size_t)NT * DD;   // 4,194,304
    const size_t half = big / 2;          // 2,097,152
    float* r_buf = p;   p += big;
    float* k_buf = p;   p += big;   // k0 -> k final in place
    float* v_buf = p;   p += big;   // v0 -> v final in place
    // x-region: 6 branch pairs (hi,lo), each pair = 'big' floats = 16 MB
    float* xreg = p;
    ushort* xrh = (ushort*)(xreg);            ushort* xrl = (ushort*)(xreg + half);
    ushort* xwh = (ushort*)(xreg + 2*half);   ushort* xwl = (ushort*)(xreg + 3*half);
    ushort* xkh = (ushort*)(xreg + 4*half);   ushort* xkl = (ushort*)(xreg + 5*half);
    ushort* xvh = (ushort*)(xreg + 6*half);   ushort* xvl = (ushort*)(xreg + 7*half);
    ushort* xah = (ushort*)(xreg + 8*half);   ushort* xal = (ushort*)(xreg + 9*half);
    ushort* xgh = (ushort*)(xreg + 10*half);  ushort* xgl = (ushort*)(xreg + 11*half);
    p += 12 * half;
    // overlays (valid after gemm_mega1 completes):
    float* w_buf   = xreg + 0 * half;   // wl -> wdec in place (16 MB over xr pair)
    float* a_buf   = xreg + 2 * half;   // over xw pair
    float* vg_buf  = xreg + 4 * half;   // over xk pair; reused as out_scan after E1
    float* os_buf  = vg_buf;
    float* g_buf   = xreg + 6 * half;   // over xv pair
    float* kkn_buf = xreg + 8 * half;   // over xa pair
    // Bt region: [3584][1024] bf16 hi + lo
    float* btreg = p;
    ushort* Bth = (ushort*)btreg;                      // 1,835,008 floats
    ushort* Btl = (ushort*)(btreg + 1835008);
    p += 2 * 1835008;
    // overlays on Bt region (valid after gemm_mega1):
    ushort* z_bf  = (ushort*)btreg;                    // 2,097,152 floats
    ushort* outTh = (ushort*)(btreg + 2097152);        // 524,288 floats
    // stage-2 transposed weights (hi/lo)
    ushort* w2Th = (ushort*)p; p += 32768; ushort* w2Tl = (ushort*)p; p += 32768;
    ushort* a2Th = (ushort*)p; p += 32768; ushort* a2Tl = (ushort*)p; p += 32768;
    ushort* v2Th = (ushort*)p; p += 16384; ushort* v2Tl = (ushort*)p; p += 16384;
    ushort* g2Th = (ushort*)p; p += 65536; ushort* g2Tl = (ushort*)p; p += 65536;
    // LoRA hidden buffers (hi/lo)
    ushort* hwh = (ushort*)p; p += 131072; ushort* hwl = (ushort*)p; p += 131072;
    ushort* hah = (ushort*)p; p += 131072; ushort* hal = (ushort*)p; p += 131072;
    ushort* hvh = (ushort*)p; p += 65536;  ushort* hvl = (ushort*)p; p += 65536;
    ushort* hgh = (ushort*)p; p += 262144; ushort* hgl = (ushort*)p; p += 262144;
    float* rks_buf = p;        p += 65536;

    dim3 blk(256);
    dim3 t32x8(32, 8);

    // ---- prep: mix6 (4096 blocks) + 11 transposes (3872 blocks) in ONE dispatch
    TJobs jobs;
    jobs.j[0]  = { rw_W, Bth + (size_t)0 * 1024,    Btl + (size_t)0 * 1024,    1024, 1024, 32, 1024 };
    jobs.j[1]  = { kw_W, Bth + (size_t)1024 * 1024, Btl + (size_t)1024 * 1024, 1024, 1024, 32, 1024 };
    jobs.j[2]  = { vw_W, Bth + (size_t)2048 * 1024, Btl + (size_t)2048 * 1024, 1024, 1024, 32, 1024 };
    jobs.j[3]  = { w1,   Bth + (size_t)3072 * 1024, Btl + (size_t)3072 * 1024, 1024, 64,   4,  128 };
    jobs.j[4]  = { a1,   Bth + (size_t)3200 * 1024, Btl + (size_t)3200 * 1024, 1024, 64,   4,  128 };
    jobs.j[5]  = { v1,   Bth + (size_t)3328 * 1024, Btl + (size_t)3328 * 1024, 1024, 32,   4,  128 };
    jobs.j[6]  = { g1,   Bth + (size_t)3456 * 1024, Btl + (size_t)3456 * 1024, 1024, 128,  4,  128 };
    jobs.j[7]  = { w2,   w2Th, w2Tl, 64,  1024, 32, 64 };
    jobs.j[8]  = { a2,   a2Th, a2Tl, 64,  1024, 32, 64 };
    jobs.j[9]  = { v2,   v2Th, v2Tl, 32,  1024, 32, 32 };
    jobs.j[10] = { g2,   g2Th, g2Tl, 128, 1024, 32, 128 };
    prep_all<<<dim3(NT + 3872), blk, 0, stream>>>(cur, prev, rwkvag,
                                                  xrh, xrl, xwh, xwl, xkh, xkl,
                                                  xvh, xvl, xah, xal, xgh, xgl, jobs);

    // ---- MEGA stage-1 GEMM (r,k,v + 4 LoRA stage-1), 128^2, counted-vmcnt dbuf
    gemm_mega1<<<dim3(32, 28), blk, 0, stream>>>(
        xrh, xrl, xwh, xwl, xkh, xkl, xvh, xvl, xah, xal, xgh, xgl,
        Bth, Btl, r_buf, k_buf, v_buf,
        hwh, hwl, hah, hal, hvh, hvl, hgh, hgl);

    // out_W transpose (Bt region is free from here on; outTh overlays Btl)
    transpose_pad<<<dim3(32, 32), t32x8, 0, stream>>>(out_W, outTh, nullptr, 1024, 1024);

    // ---- MEGA stage-2 GEMM (w2/a2/v2/g2), overwrites x-region overlays
    gemm_mega2<<<dim3(32, 32), blk, 0, stream>>>(
        hwh, hwl, hah, hal, hvh, hvl, hgh, hgl,
        w2Th, w2Tl, a2Th, a2Tl, v2Th, v2Tl, g2Th, g2Tl,
        w2_b, a2_b, v2_b, g2_b,
        w_buf, a_buf, vg_buf, g_buf);

    // ---- elementwise + scan + epilogue
    elemwise1<<<NT, blk, 0, stream>>>(r_buf, w_buf, k_buf, v_buf, kkn_buf, a_buf,
                                      vg_buf, vfirst, k_k, k_a, r_k, rks_buf);

    scan_kernel<<<dim3(64, 4), blk, 0, stream>>>(r_buf, w_buf, k_buf, kkn_buf, a_buf, v_buf,
                                                 os_buf, state_out);

    elemwise2<<<NT, blk, 0, stream>>>(os_buf, rks_buf, v_buf, g_buf, gn_s, gn_b, z_bf);

    // ---- y = z @ out_W (plain bf16, counted-vmcnt dbuf)
    gemm_bf16s<<<dim3(32, 8), blk, 0, stream>>>(z_bf, outTh, y_out, 1024, 1024);

    // ---- v_first passthrough
    hipMemcpyAsync(vf_out, vfirst, (size_t)NT * DD * sizeof(float),
                   hipMemcpyDeviceToDevice, stream);
}